// Round 12
// baseline (578.025 us; speedup 1.0000x reference)
//
#include <hip/hip_runtime.h>
#include <hip/hip_bf16.h>
#include <cfloat>

static constexpr int NBAT = 16;
static constexpr int NPT  = 2048;
static constexpr int NSEG = 4;     // pass2 n-split segments

typedef _Float16 f16;
typedef _Float16 f16x8 __attribute__((ext_vector_type(8)));
typedef float    f32x4 __attribute__((ext_vector_type(4)));

static __device__ __forceinline__ f32x4 mfma16(f16x8 a, f16x8 b, f32x4 c){
  return __builtin_amdgcn_mfma_f32_16x16x32_f16(a, b, c, 0, 0, 0);
}
// MFMA 16x16x32 f16 layouts (gfx950, e2e-verified by round-4 pass):
//  A[16r x 32k]: lane l -> row l&15, k = (l>>4)*8 + j (16B contiguous)
//  B[32k x 16c]: lane l -> col l&15, k = (l>>4)*8 + j (16B contiguous)
//  D[16r x 16c]: lane l -> col l&15, rows (l>>4)*4 + i

// ---- weight arena offsets (halfs) ----
static constexpr long OFF_M1W1 = 0;              // [128][128]
static constexpr long OFF_M2W0A= 16384;          // [128][128] (cols 0..127 of [128][256])
static constexpr long OFF_M2W1 = 32768;          // [128][128]
static constexpr long OFF_M3W0 = 49152;          // [512][384]
static constexpr long OFF_M3W1 = 245760;         // [1024][512]
static constexpr long OFF_SA   = 770048;         // per-L: wq[32][128], wv[128][128], wt[128][128]
static constexpr long SA_STRIDE= 36864;
static constexpr long WTOT     = OFF_SA + 3*SA_STRIDE;   // 880,640 halfs

// ---------------------------------------------------------------------------
// weight fp32 -> fp16 conversion into arena (one launch)
// ---------------------------------------------------------------------------
__global__ __launch_bounds__(256) void k_wconv(
    const float* m1w1, const float* m2w0, const float* m2w1,
    const float* m3w0, const float* m3w1,
    const float* wq0, const float* wv0, const float* wt0,
    const float* wq1, const float* wv1, const float* wt1,
    const float* wq2, const float* wv2, const float* wt2,
    f16* W)
{
  long t = (long)blockIdx.x*256 + threadIdx.x;
  if (t >= WTOT) return;
  float v;
  if      (t < OFF_M2W0A) v = m1w1[t];
  else if (t < OFF_M2W1) { long u = t-OFF_M2W0A; v = m2w0[(u>>7)*256 + (u&127)]; }
  else if (t < OFF_M3W0)  v = m2w1[t-OFF_M2W1];
  else if (t < OFF_M3W1)  v = m3w0[t-OFF_M3W0];
  else if (t < OFF_SA)    v = m3w1[t-OFF_M3W1];
  else {
    long u = t - OFF_SA; int L = (int)(u / SA_STRIDE); long r = u % SA_STRIDE;
    const float* wq = (L==0)?wq0:(L==1)?wq1:wq2;
    const float* wv = (L==0)?wv0:(L==1)?wv1:wv2;
    const float* wt = (L==0)?wt0:(L==1)?wt1:wt2;
    if (r < 4096) v = wq[r]; else if (r < 20480) v = wv[r-4096]; else v = wt[r-20480];
  }
  W[t] = (f16)v;
}

// ---------------------------------------------------------------------------
// mlp1 layer0 (K=3): h1T[b][n][o] = relu(b0[o] + sum_c w0[o][c]*in[b][n][c])
// ---------------------------------------------------------------------------
__global__ __launch_bounds__(256) void k_mlp1aT(const float* __restrict__ in,
                                                const float* __restrict__ w0,
                                                const float* __restrict__ b0,
                                                f16* __restrict__ h1T)
{
  long idx = (long)blockIdx.x*256 + threadIdx.x;
  int og = idx & 31; long bn = idx >> 5;
  const float* ip = in + bn*3;
  float x0=ip[0], x1=ip[1], x2=ip[2];
  f16* op = h1T + bn*128 + og*4;
  #pragma unroll
  for (int i=0;i<4;++i){
    int o = og*4+i;
    float v = b0[o] + w0[o*3]*x0 + w0[o*3+1]*x1 + w0[o*3+2]*x2;
    op[i] = (f16)fmaxf(v, 0.f);
  }
}

// ---------------------------------------------------------------------------
// generic transposed conv GEMM: OUTT[b][n][ocol+o] = act(bias + sum_k XT[b][n][k]*W[o][k])
// ---------------------------------------------------------------------------
template<int OT, bool RELU, bool B2D>
__global__ __launch_bounds__(256) void gemmT(
    const f16* __restrict__ W, const float* __restrict__ bias,
    const float* __restrict__ bias2d,
    const f16* __restrict__ XT, int xrs,
    f16* __restrict__ OUT, int ors, int ocol, int K)
{
  __shared__ __align__(16) f16 Xs[64][72];
  __shared__ __align__(16) f16 Wsh[OT][72];
  const int b  = blockIdx.z;
  const int n0 = blockIdx.x * 64;
  const int o0 = blockIdx.y * OT;
  const int tid = threadIdx.x, lane = tid & 63, w = tid >> 6;
  const int lr = lane & 15, lg = lane >> 4;
  constexpr int NSUB = (OT==64)?2:1;
  const int wn = (OT==64)? (w>>1) : w;
  const int wo = (OT==64)? (w&1) : 0;
  const int nbase = wn*(16*NSUB);
  const f16* Xb = XT + (long)b*NPT*xrs;
  f32x4 acc[NSUB][2];
  #pragma unroll
  for (int ni=0;ni<NSUB;++ni){ acc[ni][0]=(f32x4){0,0,0,0}; acc[ni][1]=(f32x4){0,0,0,0}; }

  for (int k0=0; k0<K; k0+=64){
    #pragma unroll
    for (int g = tid; g < 512; g += 256){
      int r = g>>3, s = g&7;
      *(float4*)&Xs[r][s*8] = *(const float4*)(Xb + (long)(n0+r)*xrs + k0 + s*8);
    }
    for (int g = tid; g < OT*8; g += 256){
      int r = g>>3, s = g&7;
      *(float4*)&Wsh[r][s*8] = *(const float4*)(W + (long)(o0+r)*K + k0 + s*8);
    }
    __syncthreads();
    #pragma unroll
    for (int ks=0; ks<2; ++ks){
      f16x8 a[NSUB], bf[2];
      #pragma unroll
      for (int ni=0;ni<NSUB;++ni) a[ni] = *(const f16x8*)&Xs[nbase + ni*16 + lr][ks*32 + lg*8];
      #pragma unroll
      for (int oi=0;oi<2;++oi)   bf[oi] = *(const f16x8*)&Wsh[wo*32 + oi*16 + lr][ks*32 + lg*8];
      #pragma unroll
      for (int ni=0;ni<NSUB;++ni)
        #pragma unroll
        for (int oi=0;oi<2;++oi) acc[ni][oi] = mfma16(a[ni], bf[oi], acc[ni][oi]);
    }
    __syncthreads();
  }
  #pragma unroll
  for (int ni=0;ni<NSUB;++ni)
    #pragma unroll
    for (int oi=0;oi<2;++oi){
      const int oc = o0 + wo*32 + oi*16 + lr;
      float bi = bias ? bias[oc] : 0.f;
      if constexpr (B2D) bi += bias2d[b*128 + oc];
      #pragma unroll
      for (int i=0;i<4;++i){
        const int nn = n0 + nbase + ni*16 + lg*4 + i;
        float v = acc[ni][oi][i] + bi;
        if constexpr (RELU) v = fmaxf(v, 0.f);
        OUT[(long)b*NPT*ors + (long)nn*ors + ocol + oc] = (f16)v;
      }
    }
}

// ---------------------------------------------------------------------------
// 128x128-tile GEMM (4 waves as 2x2, each wave 64x64, acc[4][4]):
// __launch_bounds__(256,4): cap regs at 128/thread -> 4 blocks/CU.
// ---------------------------------------------------------------------------
template<bool RELU>
__global__ __launch_bounds__(256, 4) void gemm128(
    const f16* __restrict__ W, const float* __restrict__ bias,
    const f16* __restrict__ XT, int xrs,
    f16* __restrict__ OUT, int ors, int K)
{
  __shared__ __align__(16) f16 Xs[128][72];
  __shared__ __align__(16) f16 Wsh[128][72];
  const int b  = blockIdx.z;
  const int n0 = blockIdx.x * 128;
  const int o0 = blockIdx.y * 128;
  const int tid = threadIdx.x, lane = tid & 63, w = tid >> 6;
  const int lr = lane & 15, lg = lane >> 4;
  const int wn = w >> 1, wo = w & 1;
  const f16* Xb = XT + (long)b*NPT*xrs;
  f32x4 acc[4][4];
  #pragma unroll
  for (int ni=0;ni<4;++ni)
    #pragma unroll
    for (int oi=0;oi<4;++oi) acc[ni][oi] = (f32x4){0,0,0,0};

  for (int k0=0; k0<K; k0+=64){
    #pragma unroll
    for (int g = tid; g < 1024; g += 256){
      int r = g>>3, s = g&7;
      *(float4*)&Xs[r][s*8]  = *(const float4*)(Xb + (long)(n0+r)*xrs + k0 + s*8);
      *(float4*)&Wsh[r][s*8] = *(const float4*)(W + (long)(o0+r)*K + k0 + s*8);
    }
    __syncthreads();
    #pragma unroll
    for (int ks=0; ks<2; ++ks){
      f16x8 a[4], bf[4];
      #pragma unroll
      for (int ni=0;ni<4;++ni) a[ni]  = *(const f16x8*)&Xs[wn*64 + ni*16 + lr][ks*32 + lg*8];
      #pragma unroll
      for (int oi=0;oi<4;++oi) bf[oi] = *(const f16x8*)&Wsh[wo*64 + oi*16 + lr][ks*32 + lg*8];
      #pragma unroll
      for (int ni=0;ni<4;++ni)
        #pragma unroll
        for (int oi=0;oi<4;++oi) acc[ni][oi] = mfma16(a[ni], bf[oi], acc[ni][oi]);
    }
    __syncthreads();
  }
  #pragma unroll
  for (int ni=0;ni<4;++ni)
    #pragma unroll
    for (int oi=0;oi<4;++oi){
      const int oc = o0 + wo*64 + oi*16 + lr;
      const float bi = bias[oc];
      #pragma unroll
      for (int i=0;i<4;++i){
        const int nn = n0 + wn*64 + ni*16 + lg*4 + i;
        float v = acc[ni][oi][i] + bi;
        if constexpr (RELU) v = fmaxf(v, 0.f);
        OUT[(long)b*NPT*ors + (long)nn*ors + oc] = (f16)v;
      }
    }
}

// ---------------------------------------------------------------------------
// mlp3 layer1 with fused max, 128x128 tile. grid (16, 8, B). K=512.
// ---------------------------------------------------------------------------
__global__ __launch_bounds__(256, 4) void k_gemmax128(
    const f16* __restrict__ W, const float* __restrict__ bias,
    const f16* __restrict__ XT, float* __restrict__ part)
{
  __shared__ __align__(16) f16 Xs[128][72];
  __shared__ __align__(16) f16 Wsh[128][72];
  __shared__ float red[2][128];
  const int b  = blockIdx.z;
  const int n0 = blockIdx.x * 128;
  const int o0 = blockIdx.y * 128;
  const int tid = threadIdx.x, lane = tid & 63, w = tid >> 6;
  const int lr = lane & 15, lg = lane >> 4;
  const int wn = w >> 1, wo = w & 1;
  const f16* Xb = XT + (long)b*NPT*512;
  f32x4 acc[4][4];
  #pragma unroll
  for (int ni=0;ni<4;++ni)
    #pragma unroll
    for (int oi=0;oi<4;++oi) acc[ni][oi] = (f32x4){0,0,0,0};

  for (int k0=0; k0<512; k0+=64){
    #pragma unroll
    for (int g = tid; g < 1024; g += 256){
      int r = g>>3, s = g&7;
      *(float4*)&Xs[r][s*8]  = *(const float4*)(Xb + (long)(n0+r)*512 + k0 + s*8);
      *(float4*)&Wsh[r][s*8] = *(const float4*)(W + (long)(o0+r)*512 + k0 + s*8);
    }
    __syncthreads();
    #pragma unroll
    for (int ks=0; ks<2; ++ks){
      f16x8 a[4], bf[4];
      #pragma unroll
      for (int ni=0;ni<4;++ni) a[ni]  = *(const f16x8*)&Xs[wn*64 + ni*16 + lr][ks*32 + lg*8];
      #pragma unroll
      for (int oi=0;oi<4;++oi) bf[oi] = *(const f16x8*)&Wsh[wo*64 + oi*16 + lr][ks*32 + lg*8];
      #pragma unroll
      for (int ni=0;ni<4;++ni)
        #pragma unroll
        for (int oi=0;oi<4;++oi) acc[ni][oi] = mfma16(a[ni], bf[oi], acc[ni][oi]);
    }
    __syncthreads();
  }
  #pragma unroll
  for (int oi=0;oi<4;++oi){
    const int oc128 = wo*64 + oi*16 + lr;
    const float bi = bias[o0 + oc128];
    float mv = -1e30f;
    #pragma unroll
    for (int ni=0;ni<4;++ni)
      #pragma unroll
      for (int i=0;i<4;++i) mv = fmaxf(mv, acc[ni][oi][i] + bi);
    mv = fmaxf(mv, __shfl_xor(mv, 16, 64));
    mv = fmaxf(mv, __shfl_xor(mv, 32, 64));
    if (lg == 0) red[wn][oc128] = mv;
  }
  __syncthreads();
  if (tid < 128)
    part[((long)b*1024 + o0 + tid)*16 + blockIdx.x] = fmaxf(red[0][tid], red[1][tid]);
}

// ---------------------------------------------------------------------------
// v GEMM, TILED output (round-6 verified): vt[b][n>>5][c][n&31]
// = bv[c] + sum_k Wv[c][k]*XT[b][n][k].  grid (32, 2, B).
// ---------------------------------------------------------------------------
__global__ __launch_bounds__(256) void vgemm(
    const f16* __restrict__ Wv, const float* __restrict__ bv,
    const f16* __restrict__ XT, f16* __restrict__ vt)
{
  __shared__ __align__(16) f16 Xs[64][72];
  __shared__ __align__(16) f16 Wsh[64][72];
  const int b  = blockIdx.z;
  const int n0 = blockIdx.x * 64;
  const int c0 = blockIdx.y * 64;
  const int tid = threadIdx.x, lane = tid & 63, w = tid >> 6;
  const int lr = lane & 15, lg = lane >> 4;
  const int wc = w>>1, wn = w&1;
  const f16* Xb = XT + (long)b*NPT*128;
  f32x4 acc[2][2];
  #pragma unroll
  for (int ci=0;ci<2;++ci){ acc[ci][0]=(f32x4){0,0,0,0}; acc[ci][1]=(f32x4){0,0,0,0}; }

  for (int k0=0; k0<128; k0+=64){
    #pragma unroll
    for (int g = tid; g < 512; g += 256){
      int r = g>>3, s = g&7;
      *(float4*)&Xs[r][s*8]  = *(const float4*)(Xb + (long)(n0+r)*128 + k0 + s*8);
      *(float4*)&Wsh[r][s*8] = *(const float4*)(Wv + (long)(c0+r)*128 + k0 + s*8);
    }
    __syncthreads();
    #pragma unroll
    for (int ks=0; ks<2; ++ks){
      f16x8 a[2], bf[2];
      #pragma unroll
      for (int ci=0;ci<2;++ci) a[ci] = *(const f16x8*)&Wsh[wc*32 + ci*16 + lr][ks*32 + lg*8];
      #pragma unroll
      for (int ni=0;ni<2;++ni) bf[ni] = *(const f16x8*)&Xs[wn*32 + ni*16 + lr][ks*32 + lg*8];
      #pragma unroll
      for (int ci=0;ci<2;++ci)
        #pragma unroll
        for (int ni=0;ni<2;++ni) acc[ci][ni] = mfma16(a[ci], bf[ni], acc[ci][ni]);
    }
    __syncthreads();
  }
  const long tb = (long)b*64 + n0/32 + wn;   // tile index (wn adds 32-n tile)
  #pragma unroll
  for (int ci=0;ci<2;++ci)
    #pragma unroll
    for (int i=0;i<4;++i){
      const int c = c0 + wc*32 + ci*16 + lg*4 + i;
      const float bi = bv[c];
      #pragma unroll
      for (int ni=0;ni<2;++ni)
        vt[(tb*128 + c)*32 + ni*16 + lr] = (f16)(acc[ci][ni][i] + bi);
    }
}

// ---------------------------------------------------------------------------
// rowstats via MFMA: rmax/rsum over m of e[m,n] (symmetric e) per col n.
// ---------------------------------------------------------------------------
__global__ __launch_bounds__(256) void k_rowstats2(const f16* __restrict__ qT,
                                                   float* __restrict__ rmax,
                                                   float* __restrict__ rsum)
{
  const int b = blockIdx.y, n0 = blockIdx.x*64;
  const int tid = threadIdx.x, lane = tid & 63, w = tid >> 6;
  const int lr = lane & 15, lg = lane >> 4;
  const f16* qb = qT + (long)b*NPT*32;
  const f16x8 bfr = *(const f16x8*)(qb + (long)(n0 + w*16 + lr)*32 + lg*8);
  float mx = -1e30f, sm = 0.f;
  for (int m0=0; m0<NPT; m0+=32){
    f16x8 af0 = *(const f16x8*)(qb + (long)(m0+lr)*32 + lg*8);
    f16x8 af1 = *(const f16x8*)(qb + (long)(m0+16+lr)*32 + lg*8);
    f32x4 e0 = mfma16(af0, bfr, (f32x4){0,0,0,0});
    f32x4 e1 = mfma16(af1, bfr, (f32x4){0,0,0,0});
    float t0 = fmaxf(fmaxf(e0[0],e0[1]), fmaxf(e0[2],e0[3]));
    float t1 = fmaxf(fmaxf(e1[0],e1[1]), fmaxf(e1[2],e1[3]));
    float nm = fmaxf(mx, fmaxf(t0, t1));
    sm *= __expf(mx - nm);
    mx = nm;
    sm += __expf(e0[0]-mx) + __expf(e0[1]-mx) + __expf(e0[2]-mx) + __expf(e0[3]-mx)
        + __expf(e1[0]-mx) + __expf(e1[1]-mx) + __expf(e1[2]-mx) + __expf(e1[3]-mx);
  }
  #pragma unroll
  for (int d=16; d<64; d<<=1){
    float omx = __shfl_xor(mx, d, 64);
    float osm = __shfl_xor(sm, d, 64);
    float nm = fmaxf(mx, omx);
    sm = sm*__expf(mx-nm) + osm*__expf(omx-nm);
    mx = nm;
  }
  if (lane < 16){
    rmax[(long)b*NPT + n0 + w*16 + lr] = mx;
    rsum[(long)b*NPT + n0 + w*16 + lr] = sm;
  }
}

// ---------------------------------------------------------------------------
// pass2 PARTIAL, sync-free: per segment seg, n in [seg*512, seg*512+512):
//   xrpart[(b*NSEG+seg)][m][c] = sum_n p[n,m] v[c,n]   (f16 raw)
//   cspart[(b*NSEG+seg)*NPT + m] = sum_n p[n,m]        (fp32, via ones-MFMA)
// No __syncthreads: ps rows are wave-private; V read direct from L2-resident
// tiled vt (round-6 verified layout). grid (32, NSEG, B).
// ---------------------------------------------------------------------------
__global__ __launch_bounds__(256) void k_pass2p(const f16* __restrict__ qT,
                                                const f16* __restrict__ vt,
                                                const float* __restrict__ rmax,
                                                const float* __restrict__ rsum,
                                                f16* __restrict__ xrpart,
                                                float* __restrict__ cspart)
{
  __shared__ __align__(16) f16 ps[64][40];   // pT[m][n-tile]; rows wave-private
  const int b = blockIdx.z, seg = blockIdx.y, m0 = blockIdx.x*64;
  const int tid = threadIdx.x, lane = tid & 63, w = tid >> 6;
  const int lr = lane & 15, lg = lane >> 4;
  const f16* qb = qT + (long)b*NPT*32;
  const f16* vb = vt + (long)b*64*128*32;
  const float* rmx = rmax + (long)b*NPT;
  const float* rsm = rsum + (long)b*NPT;
  const f16x8 afe = *(const f16x8*)(qb + (long)(m0 + w*16 + lr)*32 + lg*8);  // E A-frag (rows m)
  f16x8 ones;
  #pragma unroll
  for (int j=0;j<8;++j) ones[j] = (f16)1.0f;
  f32x4 acc[8];
  #pragma unroll
  for (int cg=0; cg<8; ++cg) acc[cg] = (f32x4){0,0,0,0};
  f32x4 acc_cs = (f32x4){0,0,0,0};

  const int ntBeg = seg*(NPT/NSEG), ntEnd = ntBeg + NPT/NSEG;
  for (int nt=ntBeg; nt<ntEnd; nt+=32){
    // E phase: 2 col-groups; D: lane col n=ng*16+lr, rows m=w*16+lg*4+i
    #pragma unroll
    for (int ng=0; ng<2; ++ng){
      f16x8 bfe = *(const f16x8*)(qb + (long)(nt + ng*16 + lr)*32 + lg*8);
      f32x4 e = mfma16(afe, bfe, (f32x4){0,0,0,0});
      const int n = nt + ng*16 + lr;
      const float rm = rmx[n];
      const float irs = 1.f / rsm[n];
      #pragma unroll
      for (int i=0;i<4;++i){
        float p = __expf(e[i] - rm) * irs;
        ps[w*16 + lg*4 + i][ng*16 + lr] = (f16)p;
      }
    }
    // transpose read (wave-private rows; compiler inserts lgkmcnt)
    f16x8 ap = *(const f16x8*)&ps[w*16 + lr][lg*8];
    // PV: B-frags direct from tiled V (1KB contiguous per wave instr, L1/L2)
    const f16* vtile = vb + (long)(nt>>5)*128*32;
    #pragma unroll
    for (int cg=0; cg<8; ++cg){
      f16x8 bp = *(const f16x8*)(vtile + (cg*16 + lr)*32 + lg*8);
      acc[cg] = mfma16(ap, bp, acc[cg]);
    }
    // colsum via ones-MFMA: D[m][*] = sum_n p[n,m] (accumulated)
    acc_cs = mfma16(ap, ones, acc_cs);
  }
  const long row = (long)(b*NSEG + seg);
  // colsum store: acc_cs[i] = cs[m0 + w*16 + lg*4 + i], duplicated across lr
  if (lr == 0){
    #pragma unroll
    for (int i=0;i<4;++i)
      cspart[row*NPT + m0 + w*16 + lg*4 + i] = acc_cs[i];
  }
  // raw partial store
  f16* xb = xrpart + row*NPT*128;
  #pragma unroll
  for (int cg=0; cg<8; ++cg)
    #pragma unroll
    for (int i=0;i<4;++i)
      xb[(long)(m0 + w*16 + lg*4 + i)*128 + cg*16 + lr] = (f16)acc[cg][i];
}

// ---------------------------------------------------------------------------
// merge NSEG partials: xrT[b][m][c] = (sum_s xrpart)/(1e-9 + sum_s cspart)
// ---------------------------------------------------------------------------
__global__ __launch_bounds__(256) void k_pmerge(const f16* __restrict__ xrpart,
                                                const float* __restrict__ cspart,
                                                f16* __restrict__ xrT)
{
  const long idx = (long)blockIdx.x*256 + threadIdx.x;   // 0..524287
  const long gm = idx >> 4;          // b*2048 + m
  const int  c0 = (int)(idx & 15) * 8;
  const long b = gm >> 11, m = gm & 2047;
  const long r0 = (b*NSEG) * (long)NPT + m;              // row base in [B*NSEG][NPT]
  float cs = 0.f;
  #pragma unroll
  for (int s=0;s<NSEG;++s) cs += cspart[r0 + (long)s*NPT];
  const float inv = 1.f/(1e-9f + cs);
  float a8[8];
  #pragma unroll
  for (int j=0;j<8;++j) a8[j] = 0.f;
  #pragma unroll
  for (int s=0;s<NSEG;++s){
    f16x8 v = *(const f16x8*)(xrpart + (r0 + (long)s*NPT)*128 + c0);
    #pragma unroll
    for (int j=0;j<8;++j) a8[j] += (float)v[j];
  }
  f16x8 ov;
  #pragma unroll
  for (int j=0;j<8;++j) ov[j] = (f16)(a8[j]*inv);
  *(f16x8*)(xrT + gm*128 + c0) = ov;
}

// ---------------------------------------------------------------------------
// xT = prev + lfT (fp16 vector add)
// ---------------------------------------------------------------------------
__global__ __launch_bounds__(256) void k_addT(const f16* __restrict__ prev, int prs, int pcol,
                                              const f16* __restrict__ lfT,
                                              f16* __restrict__ xT)
{
  long idx = (long)blockIdx.x*256 + threadIdx.x;
  long bn = idx >> 4; int c8 = (int)(idx & 15);
  f16x8 a = *(const f16x8*)(prev + bn*prs + pcol + c8*8);
  f16x8 l = *(const f16x8*)(lfT + bn*128 + c8*8);
  *(f16x8*)(xT + bn*128 + c8*8) = a + l;
}

// ---------------------------------------------------------------------------
// gmax over n per (b,c)
// ---------------------------------------------------------------------------
__global__ __launch_bounds__(1024) void k_gmaxT(const f16* __restrict__ lfT,
                                                float* __restrict__ gmaxv)
{
  __shared__ float red[8][128];
  const int b = blockIdx.x;
  const int c = threadIdx.x & 127, h = threadIdx.x >> 7;
  const f16* p = lfT + (long)b*NPT*128;
  float m = -1e30f;
  for (int n = h*256; n < (h+1)*256; ++n) m = fmaxf(m, (float)p[(long)n*128 + c]);
  red[h][c] = m; __syncthreads();
  if (threadIdx.x < 128){
    float mm = red[0][c];
    #pragma unroll
    for (int j=1;j<8;++j) mm = fmaxf(mm, red[j][c]);
    gmaxv[b*128 + c] = mm;
  }
}

__global__ __launch_bounds__(128) void k_gvec(const float* __restrict__ w0,
                                              const float* __restrict__ b0,
                                              const float* __restrict__ gmaxv,
                                              float* __restrict__ gc)
{
  const int b = blockIdx.x, o = threadIdx.x;
  __shared__ float g[128];
  g[o] = gmaxv[b*128+o]; __syncthreads();
  float acc = b0[o];
  for (int c = 0; c < 128; ++c) acc = fmaf(w0[o*256 + 128 + c], g[c], acc);
  gc[b*128+o] = acc;
}

// ---------------------------------------------------------------------------
// SA epilogue GEMM
// ---------------------------------------------------------------------------
__global__ __launch_bounds__(256) void k_safin(
    const f16* __restrict__ Wt, const float* __restrict__ bt,
    const float* __restrict__ g, const float* __restrict__ be,
    const f16* __restrict__ xT, const f16* __restrict__ xrT,
    f16* __restrict__ cat, int Lcol)
{
  __shared__ __align__(16) f16 Xs[64][72];
  __shared__ __align__(16) f16 Wsh[64][72];
  const int b  = blockIdx.z;
  const int n0 = blockIdx.x * 64;
  const int o0 = blockIdx.y * 64;
  const int tid = threadIdx.x, lane = tid & 63, w = tid >> 6;
  const int lr = lane & 15, lg = lane >> 4;
  const int wn = w>>1, wo = w&1;
  const f16* xb  = xT  + (long)b*NPT*128;
  const f16* xrb = xrT + (long)b*NPT*128;
  f32x4 acc[2][2];
  #pragma unroll
  for (int ni=0;ni<2;++ni){ acc[ni][0]=(f32x4){0,0,0,0}; acc[ni][1]=(f32x4){0,0,0,0}; }

  for (int k0=0; k0<128; k0+=64){
    #pragma unroll
    for (int gidx = tid; gidx < 512; gidx += 256){
      int r = gidx>>3, s = gidx&7;
      f16x8 xa = *(const f16x8*)(xb  + (long)(n0+r)*128 + k0 + s*8);
      f16x8 xr = *(const f16x8*)(xrb + (long)(n0+r)*128 + k0 + s*8);
      *(f16x8*)&Xs[r][s*8] = xa - xr;
      *(float4*)&Wsh[r][s*8] = *(const float4*)(Wt + (long)(o0+r)*128 + k0 + s*8);
    }
    __syncthreads();
    #pragma unroll
    for (int ks=0; ks<2; ++ks){
      f16x8 a[2], bf[2];
      #pragma unroll
      for (int ni=0;ni<2;++ni) a[ni] = *(const f16x8*)&Xs[wn*32 + ni*16 + lr][ks*32 + lg*8];
      #pragma unroll
      for (int oi=0;oi<2;++oi) bf[oi] = *(const f16x8*)&Wsh[wo*32 + oi*16 + lr][ks*32 + lg*8];
      #pragma unroll
      for (int ni=0;ni<2;++ni)
        #pragma unroll
        for (int oi=0;oi<2;++oi) acc[ni][oi] = mfma16(a[ni], bf[oi], acc[ni][oi]);
    }
    __syncthreads();
  }
  const float bnsc = rsqrtf(1.f + 1e-5f);
  #pragma unroll
  for (int ni=0;ni<2;++ni)
    #pragma unroll
    for (int oi=0;oi<2;++oi){
      const int oc = o0 + wo*32 + oi*16 + lr;
      const float bti = bt[oc], gi = g[oc]*bnsc, bei = be[oc];
      #pragma unroll
      for (int i=0;i<4;++i){
        const int nn = n0 + wn*32 + ni*16 + lg*4 + i;
        float t = acc[ni][oi][i] + bti;
        float val = fmaxf(fmaf(gi, t, bei), 0.f);
        float res = (float)xb[(long)nn*128 + oc];
        cat[(long)b*NPT*384 + (long)nn*384 + Lcol + oc] = (f16)(res + val);
      }
    }
}

__global__ __launch_bounds__(256) void k_maxfinal(const float* __restrict__ part,
                                                  float* __restrict__ out)
{
  const int t = blockIdx.x*256 + threadIdx.x;   // 0..16383
  float m = -1e30f;
  #pragma unroll
  for (int j=0;j<16;++j) m = fmaxf(m, part[(long)t*16 + j]);
  out[t] = m;
}

// ---------------------------------------------------------------------------
extern "C" void kernel_launch(void* const* d_in, const int* in_sizes, int n_in,
                              void* d_out, int out_size, void* d_ws, size_t ws_size,
                              hipStream_t stream)
{
  const float* in   = (const float*)d_in[0];
  const float* m1w0 = (const float*)d_in[1];
  const float* m1b0 = (const float*)d_in[2];
  const float* m1w1 = (const float*)d_in[3];
  const float* m1b1 = (const float*)d_in[4];
  const float* m2w0 = (const float*)d_in[5];
  const float* m2b0 = (const float*)d_in[6];
  const float* m2w1 = (const float*)d_in[7];
  const float* m2b1 = (const float*)d_in[8];
  const float* m3w0 = (const float*)d_in[9];
  const float* m3b0 = (const float*)d_in[10];
  const float* m3w1 = (const float*)d_in[11];
  const float* m3b1 = (const float*)d_in[12];

  // ws layout (halfs)
  f16* ws16 = (f16*)d_ws;
  f16* W16  = ws16;                       // 880,640
  f16* lfT  = ws16 + 880640;              // [B][N][128]
  f16* xT   = ws16 + 5074944;             // [B][N][128]
  f16* qT   = ws16 + 9269248;             // [B][N][32]
  f16* vbuf = ws16 + 10317824;            // [B][64 tiles][128][32] (tiled vt)
  f16* xrT  = ws16 + 14512128;            // [B][N][128] (also mlp2 features)
  f16* hT   = ws16 + 18706432;            // [B][N][512] (mlp hidden)
  f16* xrpart = hT;                       // [B*NSEG][N][128] — aliases hT (dead during SA)
  f16* catT = ws16 + 35483648;            // [B][N][384]
  float* fb = (float*)(ws16 + 48066560);
  float* rmaxp  = fb;                     // [B,N]
  float* rsump  = fb + 32768;             // [B,N]
  float* gmaxv  = fb + 65536;             // [B,128]
  float* gc     = fb + 67584;             // [B,128]
  float* part   = fb + 69632;             // [B,1024,16]
  float* cspart = fb + 593920;            // [B*NSEG][N]

  const dim3 blk(256);

  k_wconv<<<dim3((WTOT+255)/256), blk, 0, stream>>>(
      m1w1, m2w0, m2w1, m3w0, m3w1,
      (const float*)d_in[13], (const float*)d_in[14], (const float*)d_in[16],
      (const float*)d_in[20], (const float*)d_in[21], (const float*)d_in[23],
      (const float*)d_in[27], (const float*)d_in[28], (const float*)d_in[30],
      W16);

  // mlp1
  k_mlp1aT<<<dim3(NBAT*NPT*32/256), blk, 0, stream>>>(in, m1w0, m1b0, hT);
  gemmT<64,false,false><<<dim3(32,2,NBAT), blk, 0, stream>>>(
      W16+OFF_M1W1, m1b1, nullptr, hT, 128, lfT, 128, 0, 128);
  // global max + mlp2
  k_gmaxT<<<dim3(NBAT), dim3(1024), 0, stream>>>(lfT, gmaxv);
  k_gvec<<<dim3(NBAT), dim3(128), 0, stream>>>(m2w0, m2b0, gmaxv, gc);
  gemmT<64,true,true><<<dim3(32,2,NBAT), blk, 0, stream>>>(
      W16+OFF_M2W0A, nullptr, gc, lfT, 128, hT, 128, 0, 128);
  gemmT<64,false,false><<<dim3(32,2,NBAT), blk, 0, stream>>>(
      W16+OFF_M2W1, m2b1, nullptr, hT, 128, xrT, 128, 0, 128);   // features -> xrT

  // 3 SA layers
  for (int L = 0; L < 3; ++L){
    const float* bv = (const float*)d_in[13 + L*7 + 2];
    const float* bt = (const float*)d_in[13 + L*7 + 4];
    const float* gg = (const float*)d_in[13 + L*7 + 5];
    const float* be = (const float*)d_in[13 + L*7 + 6];
    const f16* wq16 = W16 + OFF_SA + L*SA_STRIDE;
    const f16* wv16 = wq16 + 4096;
    const f16* wt16 = wq16 + 20480;

    const f16* prev = (L==0) ? xrT : (catT + (long)(L-1)*128);
    const int  prs  = (L==0) ? 128 : 384;
    k_addT<<<dim3(NBAT*NPT*16/256), blk, 0, stream>>>(prev, prs, 0, lfT, xT);

    gemmT<32,false,false><<<dim3(32,1,NBAT), blk, 0, stream>>>(
        wq16, nullptr, nullptr, xT, 128, qT, 32, 0, 128);
    vgemm<<<dim3(32,2,NBAT), blk, 0, stream>>>(wv16, bv, xT, vbuf);
    k_rowstats2<<<dim3(32,NBAT), blk, 0, stream>>>(qT, rmaxp, rsump);
    k_pass2p<<<dim3(32,NSEG,NBAT), blk, 0, stream>>>(qT, vbuf, rmaxp, rsump, xrpart, cspart);
    k_pmerge<<<dim3(2048), blk, 0, stream>>>(xrpart, cspart, xrT);
    k_safin<<<dim3(32,2,NBAT), blk, 0, stream>>>(wt16, bt, gg, be, xT, xrT, catT, L*128);
  }

  // mlp3: layer0 (384->512 relu) 128x128 tile, layer1 fused-max 128x128
  gemm128<true><<<dim3(16,4,NBAT), blk, 0, stream>>>(
      W16+OFF_M3W0, m3b0, catT, 384, hT, 512, 384);
  k_gemmax128<<<dim3(16,8,NBAT), blk, 0, stream>>>(W16+OFF_M3W1, m3b1, hT, part);
  k_maxfinal<<<dim3(64), blk, 0, stream>>>(part, (float*)d_out);
}

// Round 13
// 501.966 us; speedup vs baseline: 1.1515x; 1.1515x over previous
//
#include <hip/hip_runtime.h>
#include <hip/hip_bf16.h>
#include <cfloat>

static constexpr int NBAT = 16;
static constexpr int NPT  = 2048;
static constexpr int NSEG = 4;     // pass2 n-split segments

typedef _Float16 f16;
typedef _Float16 f16x8 __attribute__((ext_vector_type(8)));
typedef float    f32x4 __attribute__((ext_vector_type(4)));

static __device__ __forceinline__ f32x4 mfma16(f16x8 a, f16x8 b, f32x4 c){
  return __builtin_amdgcn_mfma_f32_16x16x32_f16(a, b, c, 0, 0, 0);
}
// MFMA 16x16x32 f16 layouts (gfx950, e2e-verified by round-4 pass):
//  A[16r x 32k]: lane l -> row l&15, k = (l>>4)*8 + j (16B contiguous)
//  B[32k x 16c]: lane l -> col l&15, k = (l>>4)*8 + j (16B contiguous)
//  D[16r x 16c]: lane l -> col l&15, rows (l>>4)*4 + i

// ---- weight arena offsets (halfs) ----
static constexpr long OFF_M1W1 = 0;              // [128][128]
static constexpr long OFF_M2W0A= 16384;          // [128][128] (cols 0..127 of [128][256])
static constexpr long OFF_M2W1 = 32768;          // [128][128]
static constexpr long OFF_M3W0 = 49152;          // [512][384]
static constexpr long OFF_M3W1 = 245760;         // [1024][512]
static constexpr long OFF_SA   = 770048;         // per-L: wq[32][128], wv[128][128], wt[128][128]
static constexpr long SA_STRIDE= 36864;
static constexpr long WTOT     = OFF_SA + 3*SA_STRIDE;   // 880,640 halfs

// ---------------------------------------------------------------------------
// weight fp32 -> fp16 conversion into arena (one launch)
// ---------------------------------------------------------------------------
__global__ __launch_bounds__(256) void k_wconv(
    const float* m1w1, const float* m2w0, const float* m2w1,
    const float* m3w0, const float* m3w1,
    const float* wq0, const float* wv0, const float* wt0,
    const float* wq1, const float* wv1, const float* wt1,
    const float* wq2, const float* wv2, const float* wt2,
    f16* W)
{
  long t = (long)blockIdx.x*256 + threadIdx.x;
  if (t >= WTOT) return;
  float v;
  if      (t < OFF_M2W0A) v = m1w1[t];
  else if (t < OFF_M2W1) { long u = t-OFF_M2W0A; v = m2w0[(u>>7)*256 + (u&127)]; }
  else if (t < OFF_M3W0)  v = m2w1[t-OFF_M2W1];
  else if (t < OFF_M3W1)  v = m3w0[t-OFF_M3W0];
  else if (t < OFF_SA)    v = m3w1[t-OFF_M3W1];
  else {
    long u = t - OFF_SA; int L = (int)(u / SA_STRIDE); long r = u % SA_STRIDE;
    const float* wq = (L==0)?wq0:(L==1)?wq1:wq2;
    const float* wv = (L==0)?wv0:(L==1)?wv1:wv2;
    const float* wt = (L==0)?wt0:(L==1)?wt1:wt2;
    if (r < 4096) v = wq[r]; else if (r < 20480) v = wv[r-4096]; else v = wt[r-20480];
  }
  W[t] = (f16)v;
}

// ---------------------------------------------------------------------------
// mlp1 layer0 (K=3): h1T[b][n][o] = relu(b0[o] + sum_c w0[o][c]*in[b][n][c])
// ---------------------------------------------------------------------------
__global__ __launch_bounds__(256) void k_mlp1aT(const float* __restrict__ in,
                                                const float* __restrict__ w0,
                                                const float* __restrict__ b0,
                                                f16* __restrict__ h1T)
{
  long idx = (long)blockIdx.x*256 + threadIdx.x;
  int og = idx & 31; long bn = idx >> 5;
  const float* ip = in + bn*3;
  float x0=ip[0], x1=ip[1], x2=ip[2];
  f16* op = h1T + bn*128 + og*4;
  #pragma unroll
  for (int i=0;i<4;++i){
    int o = og*4+i;
    float v = b0[o] + w0[o*3]*x0 + w0[o*3+1]*x1 + w0[o*3+2]*x2;
    op[i] = (f16)fmaxf(v, 0.f);
  }
}

// ---------------------------------------------------------------------------
// generic transposed conv GEMM: OUTT[b][n][ocol+o] = act(bias + sum_k XT[b][n][k]*W[o][k])
// ---------------------------------------------------------------------------
template<int OT, bool RELU, bool B2D>
__global__ __launch_bounds__(256) void gemmT(
    const f16* __restrict__ W, const float* __restrict__ bias,
    const float* __restrict__ bias2d,
    const f16* __restrict__ XT, int xrs,
    f16* __restrict__ OUT, int ors, int ocol, int K)
{
  __shared__ __align__(16) f16 Xs[64][72];
  __shared__ __align__(16) f16 Wsh[OT][72];
  const int b  = blockIdx.z;
  const int n0 = blockIdx.x * 64;
  const int o0 = blockIdx.y * OT;
  const int tid = threadIdx.x, lane = tid & 63, w = tid >> 6;
  const int lr = lane & 15, lg = lane >> 4;
  constexpr int NSUB = (OT==64)?2:1;
  const int wn = (OT==64)? (w>>1) : w;
  const int wo = (OT==64)? (w&1) : 0;
  const int nbase = wn*(16*NSUB);
  const f16* Xb = XT + (long)b*NPT*xrs;
  f32x4 acc[NSUB][2];
  #pragma unroll
  for (int ni=0;ni<NSUB;++ni){ acc[ni][0]=(f32x4){0,0,0,0}; acc[ni][1]=(f32x4){0,0,0,0}; }

  for (int k0=0; k0<K; k0+=64){
    #pragma unroll
    for (int g = tid; g < 512; g += 256){
      int r = g>>3, s = g&7;
      *(float4*)&Xs[r][s*8] = *(const float4*)(Xb + (long)(n0+r)*xrs + k0 + s*8);
    }
    for (int g = tid; g < OT*8; g += 256){
      int r = g>>3, s = g&7;
      *(float4*)&Wsh[r][s*8] = *(const float4*)(W + (long)(o0+r)*K + k0 + s*8);
    }
    __syncthreads();
    #pragma unroll
    for (int ks=0; ks<2; ++ks){
      f16x8 a[NSUB], bf[2];
      #pragma unroll
      for (int ni=0;ni<NSUB;++ni) a[ni] = *(const f16x8*)&Xs[nbase + ni*16 + lr][ks*32 + lg*8];
      #pragma unroll
      for (int oi=0;oi<2;++oi)   bf[oi] = *(const f16x8*)&Wsh[wo*32 + oi*16 + lr][ks*32 + lg*8];
      #pragma unroll
      for (int ni=0;ni<NSUB;++ni)
        #pragma unroll
        for (int oi=0;oi<2;++oi) acc[ni][oi] = mfma16(a[ni], bf[oi], acc[ni][oi]);
    }
    __syncthreads();
  }
  #pragma unroll
  for (int ni=0;ni<NSUB;++ni)
    #pragma unroll
    for (int oi=0;oi<2;++oi){
      const int oc = o0 + wo*32 + oi*16 + lr;
      float bi = bias ? bias[oc] : 0.f;
      if constexpr (B2D) bi += bias2d[b*128 + oc];
      #pragma unroll
      for (int i=0;i<4;++i){
        const int nn = n0 + nbase + ni*16 + lg*4 + i;
        float v = acc[ni][oi][i] + bi;
        if constexpr (RELU) v = fmaxf(v, 0.f);
        OUT[(long)b*NPT*ors + (long)nn*ors + ocol + oc] = (f16)v;
      }
    }
}

// ---------------------------------------------------------------------------
// 128x128-tile GEMM (4 waves as 2x2, each wave 64x64, acc[4][4]):
// __launch_bounds__(256,4): cap regs at 128/thread -> 4 blocks/CU.
// ---------------------------------------------------------------------------
template<bool RELU>
__global__ __launch_bounds__(256, 4) void gemm128(
    const f16* __restrict__ W, const float* __restrict__ bias,
    const f16* __restrict__ XT, int xrs,
    f16* __restrict__ OUT, int ors, int K)
{
  __shared__ __align__(16) f16 Xs[128][72];
  __shared__ __align__(16) f16 Wsh[128][72];
  const int b  = blockIdx.z;
  const int n0 = blockIdx.x * 128;
  const int o0 = blockIdx.y * 128;
  const int tid = threadIdx.x, lane = tid & 63, w = tid >> 6;
  const int lr = lane & 15, lg = lane >> 4;
  const int wn = w >> 1, wo = w & 1;
  const f16* Xb = XT + (long)b*NPT*xrs;
  f32x4 acc[4][4];
  #pragma unroll
  for (int ni=0;ni<4;++ni)
    #pragma unroll
    for (int oi=0;oi<4;++oi) acc[ni][oi] = (f32x4){0,0,0,0};

  for (int k0=0; k0<K; k0+=64){
    #pragma unroll
    for (int g = tid; g < 1024; g += 256){
      int r = g>>3, s = g&7;
      *(float4*)&Xs[r][s*8]  = *(const float4*)(Xb + (long)(n0+r)*xrs + k0 + s*8);
      *(float4*)&Wsh[r][s*8] = *(const float4*)(W + (long)(o0+r)*K + k0 + s*8);
    }
    __syncthreads();
    #pragma unroll
    for (int ks=0; ks<2; ++ks){
      f16x8 a[4], bf[4];
      #pragma unroll
      for (int ni=0;ni<4;++ni) a[ni]  = *(const f16x8*)&Xs[wn*64 + ni*16 + lr][ks*32 + lg*8];
      #pragma unroll
      for (int oi=0;oi<4;++oi) bf[oi] = *(const f16x8*)&Wsh[wo*64 + oi*16 + lr][ks*32 + lg*8];
      #pragma unroll
      for (int ni=0;ni<4;++ni)
        #pragma unroll
        for (int oi=0;oi<4;++oi) acc[ni][oi] = mfma16(a[ni], bf[oi], acc[ni][oi]);
    }
    __syncthreads();
  }
  #pragma unroll
  for (int ni=0;ni<4;++ni)
    #pragma unroll
    for (int oi=0;oi<4;++oi){
      const int oc = o0 + wo*64 + oi*16 + lr;
      const float bi = bias[oc];
      #pragma unroll
      for (int i=0;i<4;++i){
        const int nn = n0 + wn*64 + ni*16 + lg*4 + i;
        float v = acc[ni][oi][i] + bi;
        if constexpr (RELU) v = fmaxf(v, 0.f);
        OUT[(long)b*NPT*ors + (long)nn*ors + oc] = (f16)v;
      }
    }
}

// ---------------------------------------------------------------------------
// mlp3 layer1 with fused max, 128x128 tile. grid (16, 8, B). K=512.
// ---------------------------------------------------------------------------
__global__ __launch_bounds__(256, 4) void k_gemmax128(
    const f16* __restrict__ W, const float* __restrict__ bias,
    const f16* __restrict__ XT, float* __restrict__ part)
{
  __shared__ __align__(16) f16 Xs[128][72];
  __shared__ __align__(16) f16 Wsh[128][72];
  __shared__ float red[2][128];
  const int b  = blockIdx.z;
  const int n0 = blockIdx.x * 128;
  const int o0 = blockIdx.y * 128;
  const int tid = threadIdx.x, lane = tid & 63, w = tid >> 6;
  const int lr = lane & 15, lg = lane >> 4;
  const int wn = w >> 1, wo = w & 1;
  const f16* Xb = XT + (long)b*NPT*512;
  f32x4 acc[4][4];
  #pragma unroll
  for (int ni=0;ni<4;++ni)
    #pragma unroll
    for (int oi=0;oi<4;++oi) acc[ni][oi] = (f32x4){0,0,0,0};

  for (int k0=0; k0<512; k0+=64){
    #pragma unroll
    for (int g = tid; g < 1024; g += 256){
      int r = g>>3, s = g&7;
      *(float4*)&Xs[r][s*8]  = *(const float4*)(Xb + (long)(n0+r)*512 + k0 + s*8);
      *(float4*)&Wsh[r][s*8] = *(const float4*)(W + (long)(o0+r)*512 + k0 + s*8);
    }
    __syncthreads();
    #pragma unroll
    for (int ks=0; ks<2; ++ks){
      f16x8 a[4], bf[4];
      #pragma unroll
      for (int ni=0;ni<4;++ni) a[ni]  = *(const f16x8*)&Xs[wn*64 + ni*16 + lr][ks*32 + lg*8];
      #pragma unroll
      for (int oi=0;oi<4;++oi) bf[oi] = *(const f16x8*)&Wsh[wo*64 + oi*16 + lr][ks*32 + lg*8];
      #pragma unroll
      for (int ni=0;ni<4;++ni)
        #pragma unroll
        for (int oi=0;oi<4;++oi) acc[ni][oi] = mfma16(a[ni], bf[oi], acc[ni][oi]);
    }
    __syncthreads();
  }
  #pragma unroll
  for (int oi=0;oi<4;++oi){
    const int oc128 = wo*64 + oi*16 + lr;
    const float bi = bias[o0 + oc128];
    float mv = -1e30f;
    #pragma unroll
    for (int ni=0;ni<4;++ni)
      #pragma unroll
      for (int i=0;i<4;++i) mv = fmaxf(mv, acc[ni][oi][i] + bi);
    mv = fmaxf(mv, __shfl_xor(mv, 16, 64));
    mv = fmaxf(mv, __shfl_xor(mv, 32, 64));
    if (lg == 0) red[wn][oc128] = mv;
  }
  __syncthreads();
  if (tid < 128)
    part[((long)b*1024 + o0 + tid)*16 + blockIdx.x] = fmaxf(red[0][tid], red[1][tid]);
}

// ---------------------------------------------------------------------------
// v GEMM: v16[b][c][n] = bv[c] + sum_k Wv[c][k]*XT[b][n][k]  (c rows, n cols)
// [round-11 version]
// ---------------------------------------------------------------------------
__global__ __launch_bounds__(256) void vgemm(
    const f16* __restrict__ Wv, const float* __restrict__ bv,
    const f16* __restrict__ XT, f16* __restrict__ v16)
{
  __shared__ __align__(16) f16 Xs[64][72];
  __shared__ __align__(16) f16 Wsh[64][72];
  const int b  = blockIdx.z;
  const int n0 = blockIdx.x * 64;
  const int c0 = blockIdx.y * 64;
  const int tid = threadIdx.x, lane = tid & 63, w = tid >> 6;
  const int lr = lane & 15, lg = lane >> 4;
  const int wc = w>>1, wn = w&1;
  const f16* Xb = XT + (long)b*NPT*128;
  f32x4 acc[2][2];
  #pragma unroll
  for (int ci=0;ci<2;++ci){ acc[ci][0]=(f32x4){0,0,0,0}; acc[ci][1]=(f32x4){0,0,0,0}; }

  for (int k0=0; k0<128; k0+=64){
    #pragma unroll
    for (int g = tid; g < 512; g += 256){
      int r = g>>3, s = g&7;
      *(float4*)&Xs[r][s*8]  = *(const float4*)(Xb + (long)(n0+r)*128 + k0 + s*8);
      *(float4*)&Wsh[r][s*8] = *(const float4*)(Wv + (long)(c0+r)*128 + k0 + s*8);
    }
    __syncthreads();
    #pragma unroll
    for (int ks=0; ks<2; ++ks){
      f16x8 a[2], bf[2];
      #pragma unroll
      for (int ci=0;ci<2;++ci) a[ci] = *(const f16x8*)&Wsh[wc*32 + ci*16 + lr][ks*32 + lg*8];
      #pragma unroll
      for (int ni=0;ni<2;++ni) bf[ni] = *(const f16x8*)&Xs[wn*32 + ni*16 + lr][ks*32 + lg*8];
      #pragma unroll
      for (int ci=0;ci<2;++ci)
        #pragma unroll
        for (int ni=0;ni<2;++ni) acc[ci][ni] = mfma16(a[ci], bf[ni], acc[ci][ni]);
    }
    __syncthreads();
  }
  #pragma unroll
  for (int ci=0;ci<2;++ci)
    #pragma unroll
    for (int i=0;i<4;++i){
      const int c = c0 + wc*32 + ci*16 + lg*4 + i;
      const float bi = bv[c];
      #pragma unroll
      for (int ni=0;ni<2;++ni){
        const int n = n0 + wn*32 + ni*16 + lr;
        v16[(long)b*128*NPT + (long)c*NPT + n] = (f16)(acc[ci][ni][i] + bi);
      }
    }
}

// ---------------------------------------------------------------------------
// rowstats via MFMA: rmax/rsum over m of e[m,n] (symmetric e) per col n.
// ---------------------------------------------------------------------------
__global__ __launch_bounds__(256) void k_rowstats2(const f16* __restrict__ qT,
                                                   float* __restrict__ rmax,
                                                   float* __restrict__ rsum)
{
  const int b = blockIdx.y, n0 = blockIdx.x*64;
  const int tid = threadIdx.x, lane = tid & 63, w = tid >> 6;
  const int lr = lane & 15, lg = lane >> 4;
  const f16* qb = qT + (long)b*NPT*32;
  const f16x8 bfr = *(const f16x8*)(qb + (long)(n0 + w*16 + lr)*32 + lg*8);
  float mx = -1e30f, sm = 0.f;
  for (int m0=0; m0<NPT; m0+=32){
    f16x8 af0 = *(const f16x8*)(qb + (long)(m0+lr)*32 + lg*8);
    f16x8 af1 = *(const f16x8*)(qb + (long)(m0+16+lr)*32 + lg*8);
    f32x4 e0 = mfma16(af0, bfr, (f32x4){0,0,0,0});
    f32x4 e1 = mfma16(af1, bfr, (f32x4){0,0,0,0});
    float t0 = fmaxf(fmaxf(e0[0],e0[1]), fmaxf(e0[2],e0[3]));
    float t1 = fmaxf(fmaxf(e1[0],e1[1]), fmaxf(e1[2],e1[3]));
    float nm = fmaxf(mx, fmaxf(t0, t1));
    sm *= __expf(mx - nm);
    mx = nm;
    sm += __expf(e0[0]-mx) + __expf(e0[1]-mx) + __expf(e0[2]-mx) + __expf(e0[3]-mx)
        + __expf(e1[0]-mx) + __expf(e1[1]-mx) + __expf(e1[2]-mx) + __expf(e1[3]-mx);
  }
  #pragma unroll
  for (int d=16; d<64; d<<=1){
    float omx = __shfl_xor(mx, d, 64);
    float osm = __shfl_xor(sm, d, 64);
    float nm = fmaxf(mx, omx);
    sm = sm*__expf(mx-nm) + osm*__expf(omx-nm);
    mx = nm;
  }
  if (lane < 16){
    rmax[(long)b*NPT + n0 + w*16 + lr] = mx;
    rsum[(long)b*NPT + n0 + w*16 + lr] = sm;
  }
}

// ---------------------------------------------------------------------------
// pass2 PARTIAL [round-11 structure: LDS vs staging + 2 syncs/tile]:
// per segment seg, n in [seg*512, seg*512+512):
//   xrpart[(b*NSEG+seg)][m][c] = sum_n p[n,m] v[c,n]   (f16 raw)
//   cspart[(b*NSEG+seg)*NPT + m] = sum_n p[n,m]        (fp32, ones-MFMA)
// grid (32, NSEG, B).
// ---------------------------------------------------------------------------
__global__ __launch_bounds__(256) void k_pass2p(const f16* __restrict__ qT,
                                                const f16* __restrict__ v16,
                                                const float* __restrict__ rmax,
                                                const float* __restrict__ rsum,
                                                f16* __restrict__ xrpart,
                                                float* __restrict__ cspart)
{
  __shared__ __align__(16) f16 ps[64][40];   // pT[m][n-tile]
  __shared__ __align__(16) f16 vs[128][40];  // v-tile [c][n-tile]
  const int b = blockIdx.z, seg = blockIdx.y, m0 = blockIdx.x*64;
  const int tid = threadIdx.x, lane = tid & 63, w = tid >> 6;
  const int lr = lane & 15, lg = lane >> 4;
  const f16* qb = qT + (long)b*NPT*32;
  const f16* vb = v16 + (long)b*128*NPT;
  const float* rmx = rmax + (long)b*NPT;
  const float* rsm = rsum + (long)b*NPT;
  const f16x8 afe = *(const f16x8*)(qb + (long)(m0 + w*16 + lr)*32 + lg*8);  // E A-frag (rows m)
  f16x8 ones;
  #pragma unroll
  for (int j=0;j<8;++j) ones[j] = (f16)1.0f;
  f32x4 acc[8];
  #pragma unroll
  for (int cg=0; cg<8; ++cg) acc[cg] = (f32x4){0,0,0,0};
  f32x4 acc_cs = (f32x4){0,0,0,0};

  const int ntBeg = seg*(NPT/NSEG), ntEnd = ntBeg + NPT/NSEG;
  for (int nt=ntBeg; nt<ntEnd; nt+=32){
    // stage v-tile [128c][32n] into padded LDS
    #pragma unroll
    for (int g = tid; g < 512; g += 256){
      int c = g>>2, s = g&3;
      *(float4*)&vs[c][s*8] = *(const float4*)(vb + (long)c*NPT + nt + s*8);
    }
    // E phase: 2 col-groups; lane col n fixed, 4 m-rows
    #pragma unroll
    for (int ng=0; ng<2; ++ng){
      f16x8 bfe = *(const f16x8*)(qb + (long)(nt + ng*16 + lr)*32 + lg*8);
      f32x4 e = mfma16(afe, bfe, (f32x4){0,0,0,0});
      const int n = nt + ng*16 + lr;
      const float rm = rmx[n];
      const float irs = 1.f / rsm[n];
      #pragma unroll
      for (int i=0;i<4;++i){
        float p = __expf(e[i] - rm) * irs;
        ps[w*16 + lg*4 + i][ng*16 + lr] = (f16)p;
      }
    }
    __syncthreads();
    // PV phase: A = pT rows m (wave-private), B = v-tile cols c
    f16x8 ap = *(const f16x8*)&ps[w*16 + lr][lg*8];
    #pragma unroll
    for (int cg=0; cg<8; ++cg){
      f16x8 bp = *(const f16x8*)&vs[cg*16 + lr][lg*8];
      acc[cg] = mfma16(ap, bp, acc[cg]);
    }
    // colsum via ones-MFMA (removes 16 VALU ops/tile from hot pipe)
    acc_cs = mfma16(ap, ones, acc_cs);
    __syncthreads();
  }
  const long row = (long)(b*NSEG + seg);
  // acc_cs[i] = cs[m0 + w*16 + lg*4 + i], duplicated across lr
  if (lr == 0){
    #pragma unroll
    for (int i=0;i<4;++i)
      cspart[row*NPT + m0 + w*16 + lg*4 + i] = acc_cs[i];
  }
  // raw partial store (no renorm)
  f16* xb = xrpart + row*NPT*128;
  #pragma unroll
  for (int cg=0; cg<8; ++cg)
    #pragma unroll
    for (int i=0;i<4;++i)
      xb[(long)(m0 + w*16 + lg*4 + i)*128 + cg*16 + lr] = (f16)acc[cg][i];
}

// ---------------------------------------------------------------------------
// merge NSEG partials: xrT[b][m][c] = (sum_s xrpart)/(1e-9 + sum_s cspart)
// ---------------------------------------------------------------------------
__global__ __launch_bounds__(256) void k_pmerge(const f16* __restrict__ xrpart,
                                                const float* __restrict__ cspart,
                                                f16* __restrict__ xrT)
{
  const long idx = (long)blockIdx.x*256 + threadIdx.x;   // 0..524287
  const long gm = idx >> 4;          // b*2048 + m
  const int  c0 = (int)(idx & 15) * 8;
  const long b = gm >> 11, m = gm & 2047;
  const long r0 = (b*NSEG) * (long)NPT + m;              // row base in [B*NSEG][NPT]
  float cs = 0.f;
  #pragma unroll
  for (int s=0;s<NSEG;++s) cs += cspart[r0 + (long)s*NPT];
  const float inv = 1.f/(1e-9f + cs);
  float a8[8];
  #pragma unroll
  for (int j=0;j<8;++j) a8[j] = 0.f;
  #pragma unroll
  for (int s=0;s<NSEG;++s){
    f16x8 v = *(const f16x8*)(xrpart + (r0 + (long)s*NPT)*128 + c0);
    #pragma unroll
    for (int j=0;j<8;++j) a8[j] += (float)v[j];
  }
  f16x8 ov;
  #pragma unroll
  for (int j=0;j<8;++j) ov[j] = (f16)(a8[j]*inv);
  *(f16x8*)(xrT + gm*128 + c0) = ov;
}

// ---------------------------------------------------------------------------
// xT = prev + lfT (fp16 vector add)
// ---------------------------------------------------------------------------
__global__ __launch_bounds__(256) void k_addT(const f16* __restrict__ prev, int prs, int pcol,
                                              const f16* __restrict__ lfT,
                                              f16* __restrict__ xT)
{
  long idx = (long)blockIdx.x*256 + threadIdx.x;
  long bn = idx >> 4; int c8 = (int)(idx & 15);
  f16x8 a = *(const f16x8*)(prev + bn*prs + pcol + c8*8);
  f16x8 l = *(const f16x8*)(lfT + bn*128 + c8*8);
  *(f16x8*)(xT + bn*128 + c8*8) = a + l;
}

// ---------------------------------------------------------------------------
// gmax over n per (b,c)
// ---------------------------------------------------------------------------
__global__ __launch_bounds__(1024) void k_gmaxT(const f16* __restrict__ lfT,
                                                float* __restrict__ gmaxv)
{
  __shared__ float red[8][128];
  const int b = blockIdx.x;
  const int c = threadIdx.x & 127, h = threadIdx.x >> 7;
  const f16* p = lfT + (long)b*NPT*128;
  float m = -1e30f;
  for (int n = h*256; n < (h+1)*256; ++n) m = fmaxf(m, (float)p[(long)n*128 + c]);
  red[h][c] = m; __syncthreads();
  if (threadIdx.x < 128){
    float mm = red[0][c];
    #pragma unroll
    for (int j=1;j<8;++j) mm = fmaxf(mm, red[j][c]);
    gmaxv[b*128 + c] = mm;
  }
}

__global__ __launch_bounds__(128) void k_gvec(const float* __restrict__ w0,
                                              const float* __restrict__ b0,
                                              const float* __restrict__ gmaxv,
                                              float* __restrict__ gc)
{
  const int b = blockIdx.x, o = threadIdx.x;
  __shared__ float g[128];
  g[o] = gmaxv[b*128+o]; __syncthreads();
  float acc = b0[o];
  for (int c = 0; c < 128; ++c) acc = fmaf(w0[o*256 + 128 + c], g[c], acc);
  gc[b*128+o] = acc;
}

// ---------------------------------------------------------------------------
// SA epilogue GEMM
// ---------------------------------------------------------------------------
__global__ __launch_bounds__(256) void k_safin(
    const f16* __restrict__ Wt, const float* __restrict__ bt,
    const float* __restrict__ g, const float* __restrict__ be,
    const f16* __restrict__ xT, const f16* __restrict__ xrT,
    f16* __restrict__ cat, int Lcol)
{
  __shared__ __align__(16) f16 Xs[64][72];
  __shared__ __align__(16) f16 Wsh[64][72];
  const int b  = blockIdx.z;
  const int n0 = blockIdx.x * 64;
  const int o0 = blockIdx.y * 64;
  const int tid = threadIdx.x, lane = tid & 63, w = tid >> 6;
  const int lr = lane & 15, lg = lane >> 4;
  const int wn = w>>1, wo = w&1;
  const f16* xb  = xT  + (long)b*NPT*128;
  const f16* xrb = xrT + (long)b*NPT*128;
  f32x4 acc[2][2];
  #pragma unroll
  for (int ni=0;ni<2;++ni){ acc[ni][0]=(f32x4){0,0,0,0}; acc[ni][1]=(f32x4){0,0,0,0}; }

  for (int k0=0; k0<128; k0+=64){
    #pragma unroll
    for (int gidx = tid; gidx < 512; gidx += 256){
      int r = gidx>>3, s = gidx&7;
      f16x8 xa = *(const f16x8*)(xb  + (long)(n0+r)*128 + k0 + s*8);
      f16x8 xr = *(const f16x8*)(xrb + (long)(n0+r)*128 + k0 + s*8);
      *(f16x8*)&Xs[r][s*8] = xa - xr;
      *(float4*)&Wsh[r][s*8] = *(const float4*)(Wt + (long)(o0+r)*128 + k0 + s*8);
    }
    __syncthreads();
    #pragma unroll
    for (int ks=0; ks<2; ++ks){
      f16x8 a[2], bf[2];
      #pragma unroll
      for (int ni=0;ni<2;++ni) a[ni] = *(const f16x8*)&Xs[wn*32 + ni*16 + lr][ks*32 + lg*8];
      #pragma unroll
      for (int oi=0;oi<2;++oi) bf[oi] = *(const f16x8*)&Wsh[wo*32 + oi*16 + lr][ks*32 + lg*8];
      #pragma unroll
      for (int ni=0;ni<2;++ni)
        #pragma unroll
        for (int oi=0;oi<2;++oi) acc[ni][oi] = mfma16(a[ni], bf[oi], acc[ni][oi]);
    }
    __syncthreads();
  }
  const float bnsc = rsqrtf(1.f + 1e-5f);
  #pragma unroll
  for (int ni=0;ni<2;++ni)
    #pragma unroll
    for (int oi=0;oi<2;++oi){
      const int oc = o0 + wo*32 + oi*16 + lr;
      const float bti = bt[oc], gi = g[oc]*bnsc, bei = be[oc];
      #pragma unroll
      for (int i=0;i<4;++i){
        const int nn = n0 + wn*32 + ni*16 + lg*4 + i;
        float t = acc[ni][oi][i] + bti;
        float val = fmaxf(fmaf(gi, t, bei), 0.f);
        float res = (float)xb[(long)nn*128 + oc];
        cat[(long)b*NPT*384 + (long)nn*384 + Lcol + oc] = (f16)(res + val);
      }
    }
}

__global__ __launch_bounds__(256) void k_maxfinal(const float* __restrict__ part,
                                                  float* __restrict__ out)
{
  const int t = blockIdx.x*256 + threadIdx.x;   // 0..16383
  float m = -1e30f;
  #pragma unroll
  for (int j=0;j<16;++j) m = fmaxf(m, part[(long)t*16 + j]);
  out[t] = m;
}

// ---------------------------------------------------------------------------
extern "C" void kernel_launch(void* const* d_in, const int* in_sizes, int n_in,
                              void* d_out, int out_size, void* d_ws, size_t ws_size,
                              hipStream_t stream)
{
  const float* in   = (const float*)d_in[0];
  const float* m1w0 = (const float*)d_in[1];
  const float* m1b0 = (const float*)d_in[2];
  const float* m1w1 = (const float*)d_in[3];
  const float* m1b1 = (const float*)d_in[4];
  const float* m2w0 = (const float*)d_in[5];
  const float* m2b0 = (const float*)d_in[6];
  const float* m2w1 = (const float*)d_in[7];
  const float* m2b1 = (const float*)d_in[8];
  const float* m3w0 = (const float*)d_in[9];
  const float* m3b0 = (const float*)d_in[10];
  const float* m3w1 = (const float*)d_in[11];
  const float* m3b1 = (const float*)d_in[12];

  // ws layout (halfs)
  f16* ws16 = (f16*)d_ws;
  f16* W16  = ws16;                       // 880,640
  f16* lfT  = ws16 + 880640;              // [B][N][128]
  f16* xT   = ws16 + 5074944;             // [B][N][128]
  f16* qT   = ws16 + 9269248;             // [B][N][32]
  f16* vbuf = ws16 + 10317824;            // [B][128][N]
  f16* xrT  = ws16 + 14512128;            // [B][N][128] (also mlp2 features)
  f16* hT   = ws16 + 18706432;            // [B][N][512] (mlp hidden)
  f16* xrpart = hT;                       // [B*NSEG][N][128] — aliases hT (dead during SA)
  f16* catT = ws16 + 35483648;            // [B][N][384]
  float* fb = (float*)(ws16 + 48066560);
  float* rmaxp  = fb;                     // [B,N]
  float* rsump  = fb + 32768;             // [B,N]
  float* gmaxv  = fb + 65536;             // [B,128]
  float* gc     = fb + 67584;             // [B,128]
  float* part   = fb + 69632;             // [B,1024,16]
  float* cspart = fb + 593920;            // [B*NSEG][N]

  const dim3 blk(256);

  k_wconv<<<dim3((WTOT+255)/256), blk, 0, stream>>>(
      m1w1, m2w0, m2w1, m3w0, m3w1,
      (const float*)d_in[13], (const float*)d_in[14], (const float*)d_in[16],
      (const float*)d_in[20], (const float*)d_in[21], (const float*)d_in[23],
      (const float*)d_in[27], (const float*)d_in[28], (const float*)d_in[30],
      W16);

  // mlp1
  k_mlp1aT<<<dim3(NBAT*NPT*32/256), blk, 0, stream>>>(in, m1w0, m1b0, hT);
  gemmT<64,false,false><<<dim3(32,2,NBAT), blk, 0, stream>>>(
      W16+OFF_M1W1, m1b1, nullptr, hT, 128, lfT, 128, 0, 128);
  // global max + mlp2
  k_gmaxT<<<dim3(NBAT), dim3(1024), 0, stream>>>(lfT, gmaxv);
  k_gvec<<<dim3(NBAT), dim3(128), 0, stream>>>(m2w0, m2b0, gmaxv, gc);
  gemmT<64,true,true><<<dim3(32,2,NBAT), blk, 0, stream>>>(
      W16+OFF_M2W0A, nullptr, gc, lfT, 128, hT, 128, 0, 128);
  gemmT<64,false,false><<<dim3(32,2,NBAT), blk, 0, stream>>>(
      W16+OFF_M2W1, m2b1, nullptr, hT, 128, xrT, 128, 0, 128);   // features -> xrT

  // 3 SA layers
  for (int L = 0; L < 3; ++L){
    const float* bv = (const float*)d_in[13 + L*7 + 2];
    const float* bt = (const float*)d_in[13 + L*7 + 4];
    const float* gg = (const float*)d_in[13 + L*7 + 5];
    const float* be = (const float*)d_in[13 + L*7 + 6];
    const f16* wq16 = W16 + OFF_SA + L*SA_STRIDE;
    const f16* wv16 = wq16 + 4096;
    const f16* wt16 = wq16 + 20480;

    const f16* prev = (L==0) ? xrT : (catT + (long)(L-1)*128);
    const int  prs  = (L==0) ? 128 : 384;
    k_addT<<<dim3(NBAT*NPT*16/256), blk, 0, stream>>>(prev, prs, 0, lfT, xT);

    gemmT<32,false,false><<<dim3(32,1,NBAT), blk, 0, stream>>>(
        wq16, nullptr, nullptr, xT, 128, qT, 32, 0, 128);
    vgemm<<<dim3(32,2,NBAT), blk, 0, stream>>>(wv16, bv, xT, vbuf);
    k_rowstats2<<<dim3(32,NBAT), blk, 0, stream>>>(qT, rmaxp, rsump);
    k_pass2p<<<dim3(32,NSEG,NBAT), blk, 0, stream>>>(qT, vbuf, rmaxp, rsump, xrpart, cspart);
    k_pmerge<<<dim3(2048), blk, 0, stream>>>(xrpart, cspart, xrT);
    k_safin<<<dim3(32,2,NBAT), blk, 0, stream>>>(wt16, bt, gg, be, xT, xrT, catT, L*128);
  }

  // mlp3: layer0 (384->512 relu) 128x128 tile, layer1 fused-max 128x128
  gemm128<true><<<dim3(16,4,NBAT), blk, 0, stream>>>(
      W16+OFF_M3W0, m3b0, catT, 384, hT, 512, 384);
  k_gemmax128<<<dim3(16,8,NBAT), blk, 0, stream>>>(W16+OFF_M3W1, m3b1, hT, part);
  k_maxfinal<<<dim3(64), blk, 0, stream>>>(part, (float*)d_out);
}

// Round 14
// 497.647 us; speedup vs baseline: 1.1615x; 1.0087x over previous
//
#include <hip/hip_runtime.h>
#include <hip/hip_bf16.h>
#include <cfloat>

static constexpr int NBAT = 16;
static constexpr int NPT  = 2048;
static constexpr int NSEG = 4;     // pass2 n-split segments

typedef _Float16 f16;
typedef _Float16 f16x8 __attribute__((ext_vector_type(8)));
typedef float    f32x4 __attribute__((ext_vector_type(4)));

static __device__ __forceinline__ f32x4 mfma16(f16x8 a, f16x8 b, f32x4 c){
  return __builtin_amdgcn_mfma_f32_16x16x32_f16(a, b, c, 0, 0, 0);
}
// MFMA 16x16x32 f16 layouts (gfx950, e2e-verified by round-4 pass):
//  A[16r x 32k]: lane l -> row l&15, k = (l>>4)*8 + j (16B contiguous)
//  B[32k x 16c]: lane l -> col l&15, k = (l>>4)*8 + j (16B contiguous)
//  D[16r x 16c]: lane l -> col l&15, rows (l>>4)*4 + i

// ---- weight arena offsets (halfs) ----
static constexpr long OFF_M1W1 = 0;              // [128][128]
static constexpr long OFF_M2W0A= 16384;          // [128][128] (cols 0..127 of [128][256])
static constexpr long OFF_M2W1 = 32768;          // [128][128]
static constexpr long OFF_M3W0 = 49152;          // [512][384]
static constexpr long OFF_M3W1 = 245760;         // [1024][512]
static constexpr long OFF_SA   = 770048;         // per-L: wq[32][128], wv[128][128], wt[128][128]
static constexpr long SA_STRIDE= 36864;
static constexpr long WTOT     = OFF_SA + 3*SA_STRIDE;   // 880,640 halfs

// ---------------------------------------------------------------------------
// weight fp32 -> fp16 conversion into arena (one launch)
// ---------------------------------------------------------------------------
__global__ __launch_bounds__(256) void k_wconv(
    const float* m1w1, const float* m2w0, const float* m2w1,
    const float* m3w0, const float* m3w1,
    const float* wq0, const float* wv0, const float* wt0,
    const float* wq1, const float* wv1, const float* wt1,
    const float* wq2, const float* wv2, const float* wt2,
    f16* W)
{
  long t = (long)blockIdx.x*256 + threadIdx.x;
  if (t >= WTOT) return;
  float v;
  if      (t < OFF_M2W0A) v = m1w1[t];
  else if (t < OFF_M2W1) { long u = t-OFF_M2W0A; v = m2w0[(u>>7)*256 + (u&127)]; }
  else if (t < OFF_M3W0)  v = m2w1[t-OFF_M2W1];
  else if (t < OFF_M3W1)  v = m3w0[t-OFF_M3W0];
  else if (t < OFF_SA)    v = m3w1[t-OFF_M3W1];
  else {
    long u = t - OFF_SA; int L = (int)(u / SA_STRIDE); long r = u % SA_STRIDE;
    const float* wq = (L==0)?wq0:(L==1)?wq1:wq2;
    const float* wv = (L==0)?wv0:(L==1)?wv1:wv2;
    const float* wt = (L==0)?wt0:(L==1)?wt1:wt2;
    if (r < 4096) v = wq[r]; else if (r < 20480) v = wv[r-4096]; else v = wt[r-20480];
  }
  W[t] = (f16)v;
}

// ---------------------------------------------------------------------------
// mlp1 layer0 (K=3): h1T[b][n][o] = relu(b0[o] + sum_c w0[o][c]*in[b][n][c])
// ---------------------------------------------------------------------------
__global__ __launch_bounds__(256) void k_mlp1aT(const float* __restrict__ in,
                                                const float* __restrict__ w0,
                                                const float* __restrict__ b0,
                                                f16* __restrict__ h1T)
{
  long idx = (long)blockIdx.x*256 + threadIdx.x;
  int og = idx & 31; long bn = idx >> 5;
  const float* ip = in + bn*3;
  float x0=ip[0], x1=ip[1], x2=ip[2];
  f16* op = h1T + bn*128 + og*4;
  #pragma unroll
  for (int i=0;i<4;++i){
    int o = og*4+i;
    float v = b0[o] + w0[o*3]*x0 + w0[o*3+1]*x1 + w0[o*3+2]*x2;
    op[i] = (f16)fmaxf(v, 0.f);
  }
}

// ---------------------------------------------------------------------------
// generic transposed conv GEMM: OUTT[b][n][ocol+o] = act(bias + sum_k XT[b][n][k]*W[o][k])
// ---------------------------------------------------------------------------
template<int OT, bool RELU, bool B2D>
__global__ __launch_bounds__(256) void gemmT(
    const f16* __restrict__ W, const float* __restrict__ bias,
    const float* __restrict__ bias2d,
    const f16* __restrict__ XT, int xrs,
    f16* __restrict__ OUT, int ors, int ocol, int K)
{
  __shared__ __align__(16) f16 Xs[64][72];
  __shared__ __align__(16) f16 Wsh[OT][72];
  const int b  = blockIdx.z;
  const int n0 = blockIdx.x * 64;
  const int o0 = blockIdx.y * OT;
  const int tid = threadIdx.x, lane = tid & 63, w = tid >> 6;
  const int lr = lane & 15, lg = lane >> 4;
  constexpr int NSUB = (OT==64)?2:1;
  const int wn = (OT==64)? (w>>1) : w;
  const int wo = (OT==64)? (w&1) : 0;
  const int nbase = wn*(16*NSUB);
  const f16* Xb = XT + (long)b*NPT*xrs;
  f32x4 acc[NSUB][2];
  #pragma unroll
  for (int ni=0;ni<NSUB;++ni){ acc[ni][0]=(f32x4){0,0,0,0}; acc[ni][1]=(f32x4){0,0,0,0}; }

  for (int k0=0; k0<K; k0+=64){
    #pragma unroll
    for (int g = tid; g < 512; g += 256){
      int r = g>>3, s = g&7;
      *(float4*)&Xs[r][s*8] = *(const float4*)(Xb + (long)(n0+r)*xrs + k0 + s*8);
    }
    for (int g = tid; g < OT*8; g += 256){
      int r = g>>3, s = g&7;
      *(float4*)&Wsh[r][s*8] = *(const float4*)(W + (long)(o0+r)*K + k0 + s*8);
    }
    __syncthreads();
    #pragma unroll
    for (int ks=0; ks<2; ++ks){
      f16x8 a[NSUB], bf[2];
      #pragma unroll
      for (int ni=0;ni<NSUB;++ni) a[ni] = *(const f16x8*)&Xs[nbase + ni*16 + lr][ks*32 + lg*8];
      #pragma unroll
      for (int oi=0;oi<2;++oi)   bf[oi] = *(const f16x8*)&Wsh[wo*32 + oi*16 + lr][ks*32 + lg*8];
      #pragma unroll
      for (int ni=0;ni<NSUB;++ni)
        #pragma unroll
        for (int oi=0;oi<2;++oi) acc[ni][oi] = mfma16(a[ni], bf[oi], acc[ni][oi]);
    }
    __syncthreads();
  }
  #pragma unroll
  for (int ni=0;ni<NSUB;++ni)
    #pragma unroll
    for (int oi=0;oi<2;++oi){
      const int oc = o0 + wo*32 + oi*16 + lr;
      float bi = bias ? bias[oc] : 0.f;
      if constexpr (B2D) bi += bias2d[b*128 + oc];
      #pragma unroll
      for (int i=0;i<4;++i){
        const int nn = n0 + nbase + ni*16 + lg*4 + i;
        float v = acc[ni][oi][i] + bi;
        if constexpr (RELU) v = fmaxf(v, 0.f);
        OUT[(long)b*NPT*ors + (long)nn*ors + ocol + oc] = (f16)v;
      }
    }
}

// ---------------------------------------------------------------------------
// 128x128-tile GEMM (4 waves as 2x2, each wave 64x64, acc[4][4]):
// __launch_bounds__(256,4): cap regs at 128/thread -> 4 blocks/CU.
// ---------------------------------------------------------------------------
template<bool RELU>
__global__ __launch_bounds__(256, 4) void gemm128(
    const f16* __restrict__ W, const float* __restrict__ bias,
    const f16* __restrict__ XT, int xrs,
    f16* __restrict__ OUT, int ors, int K)
{
  __shared__ __align__(16) f16 Xs[128][72];
  __shared__ __align__(16) f16 Wsh[128][72];
  const int b  = blockIdx.z;
  const int n0 = blockIdx.x * 128;
  const int o0 = blockIdx.y * 128;
  const int tid = threadIdx.x, lane = tid & 63, w = tid >> 6;
  const int lr = lane & 15, lg = lane >> 4;
  const int wn = w >> 1, wo = w & 1;
  const f16* Xb = XT + (long)b*NPT*xrs;
  f32x4 acc[4][4];
  #pragma unroll
  for (int ni=0;ni<4;++ni)
    #pragma unroll
    for (int oi=0;oi<4;++oi) acc[ni][oi] = (f32x4){0,0,0,0};

  for (int k0=0; k0<K; k0+=64){
    #pragma unroll
    for (int g = tid; g < 1024; g += 256){
      int r = g>>3, s = g&7;
      *(float4*)&Xs[r][s*8]  = *(const float4*)(Xb + (long)(n0+r)*xrs + k0 + s*8);
      *(float4*)&Wsh[r][s*8] = *(const float4*)(W + (long)(o0+r)*K + k0 + s*8);
    }
    __syncthreads();
    #pragma unroll
    for (int ks=0; ks<2; ++ks){
      f16x8 a[4], bf[4];
      #pragma unroll
      for (int ni=0;ni<4;++ni) a[ni]  = *(const f16x8*)&Xs[wn*64 + ni*16 + lr][ks*32 + lg*8];
      #pragma unroll
      for (int oi=0;oi<4;++oi) bf[oi] = *(const f16x8*)&Wsh[wo*64 + oi*16 + lr][ks*32 + lg*8];
      #pragma unroll
      for (int ni=0;ni<4;++ni)
        #pragma unroll
        for (int oi=0;oi<4;++oi) acc[ni][oi] = mfma16(a[ni], bf[oi], acc[ni][oi]);
    }
    __syncthreads();
  }
  #pragma unroll
  for (int ni=0;ni<4;++ni)
    #pragma unroll
    for (int oi=0;oi<4;++oi){
      const int oc = o0 + wo*64 + oi*16 + lr;
      const float bi = bias[oc];
      #pragma unroll
      for (int i=0;i<4;++i){
        const int nn = n0 + wn*64 + ni*16 + lg*4 + i;
        float v = acc[ni][oi][i] + bi;
        if constexpr (RELU) v = fmaxf(v, 0.f);
        OUT[(long)b*NPT*ors + (long)nn*ors + oc] = (f16)v;
      }
    }
}

// ---------------------------------------------------------------------------
// mlp3 layer1 with fused max, 128x128 tile. grid (16, 8, B). K=512.
// ---------------------------------------------------------------------------
__global__ __launch_bounds__(256, 4) void k_gemmax128(
    const f16* __restrict__ W, const float* __restrict__ bias,
    const f16* __restrict__ XT, float* __restrict__ part)
{
  __shared__ __align__(16) f16 Xs[128][72];
  __shared__ __align__(16) f16 Wsh[128][72];
  __shared__ float red[2][128];
  const int b  = blockIdx.z;
  const int n0 = blockIdx.x * 128;
  const int o0 = blockIdx.y * 128;
  const int tid = threadIdx.x, lane = tid & 63, w = tid >> 6;
  const int lr = lane & 15, lg = lane >> 4;
  const int wn = w >> 1, wo = w & 1;
  const f16* Xb = XT + (long)b*NPT*512;
  f32x4 acc[4][4];
  #pragma unroll
  for (int ni=0;ni<4;++ni)
    #pragma unroll
    for (int oi=0;oi<4;++oi) acc[ni][oi] = (f32x4){0,0,0,0};

  for (int k0=0; k0<512; k0+=64){
    #pragma unroll
    for (int g = tid; g < 1024; g += 256){
      int r = g>>3, s = g&7;
      *(float4*)&Xs[r][s*8]  = *(const float4*)(Xb + (long)(n0+r)*512 + k0 + s*8);
      *(float4*)&Wsh[r][s*8] = *(const float4*)(W + (long)(o0+r)*512 + k0 + s*8);
    }
    __syncthreads();
    #pragma unroll
    for (int ks=0; ks<2; ++ks){
      f16x8 a[4], bf[4];
      #pragma unroll
      for (int ni=0;ni<4;++ni) a[ni]  = *(const f16x8*)&Xs[wn*64 + ni*16 + lr][ks*32 + lg*8];
      #pragma unroll
      for (int oi=0;oi<4;++oi) bf[oi] = *(const f16x8*)&Wsh[wo*64 + oi*16 + lr][ks*32 + lg*8];
      #pragma unroll
      for (int ni=0;ni<4;++ni)
        #pragma unroll
        for (int oi=0;oi<4;++oi) acc[ni][oi] = mfma16(a[ni], bf[oi], acc[ni][oi]);
    }
    __syncthreads();
  }
  #pragma unroll
  for (int oi=0;oi<4;++oi){
    const int oc128 = wo*64 + oi*16 + lr;
    const float bi = bias[o0 + oc128];
    float mv = -1e30f;
    #pragma unroll
    for (int ni=0;ni<4;++ni)
      #pragma unroll
      for (int i=0;i<4;++i) mv = fmaxf(mv, acc[ni][oi][i] + bi);
    mv = fmaxf(mv, __shfl_xor(mv, 16, 64));
    mv = fmaxf(mv, __shfl_xor(mv, 32, 64));
    if (lg == 0) red[wn][oc128] = mv;
  }
  __syncthreads();
  if (tid < 128)
    part[((long)b*1024 + o0 + tid)*16 + blockIdx.x] = fmaxf(red[0][tid], red[1][tid]);
}

// ---------------------------------------------------------------------------
// v GEMM: v16[b][c][n] = bv[c] + sum_k Wv[c][k]*XT[b][n][k]  (c rows, n cols)
// ---------------------------------------------------------------------------
__global__ __launch_bounds__(256) void vgemm(
    const f16* __restrict__ Wv, const float* __restrict__ bv,
    const f16* __restrict__ XT, f16* __restrict__ v16)
{
  __shared__ __align__(16) f16 Xs[64][72];
  __shared__ __align__(16) f16 Wsh[64][72];
  const int b  = blockIdx.z;
  const int n0 = blockIdx.x * 64;
  const int c0 = blockIdx.y * 64;
  const int tid = threadIdx.x, lane = tid & 63, w = tid >> 6;
  const int lr = lane & 15, lg = lane >> 4;
  const int wc = w>>1, wn = w&1;
  const f16* Xb = XT + (long)b*NPT*128;
  f32x4 acc[2][2];
  #pragma unroll
  for (int ci=0;ci<2;++ci){ acc[ci][0]=(f32x4){0,0,0,0}; acc[ci][1]=(f32x4){0,0,0,0}; }

  for (int k0=0; k0<128; k0+=64){
    #pragma unroll
    for (int g = tid; g < 512; g += 256){
      int r = g>>3, s = g&7;
      *(float4*)&Xs[r][s*8]  = *(const float4*)(Xb + (long)(n0+r)*128 + k0 + s*8);
      *(float4*)&Wsh[r][s*8] = *(const float4*)(Wv + (long)(c0+r)*128 + k0 + s*8);
    }
    __syncthreads();
    #pragma unroll
    for (int ks=0; ks<2; ++ks){
      f16x8 a[2], bf[2];
      #pragma unroll
      for (int ci=0;ci<2;++ci) a[ci] = *(const f16x8*)&Wsh[wc*32 + ci*16 + lr][ks*32 + lg*8];
      #pragma unroll
      for (int ni=0;ni<2;++ni) bf[ni] = *(const f16x8*)&Xs[wn*32 + ni*16 + lr][ks*32 + lg*8];
      #pragma unroll
      for (int ci=0;ci<2;++ci)
        #pragma unroll
        for (int ni=0;ni<2;++ni) acc[ci][ni] = mfma16(a[ci], bf[ni], acc[ci][ni]);
    }
    __syncthreads();
  }
  #pragma unroll
  for (int ci=0;ci<2;++ci)
    #pragma unroll
    for (int i=0;i<4;++i){
      const int c = c0 + wc*32 + ci*16 + lg*4 + i;
      const float bi = bv[c];
      #pragma unroll
      for (int ni=0;ni<2;++ni){
        const int n = n0 + wn*32 + ni*16 + lr;
        v16[(long)b*128*NPT + (long)c*NPT + n] = (f16)(acc[ci][ni][i] + bi);
      }
    }
}

// ---------------------------------------------------------------------------
// rowstats via MFMA: rmax/rsum over m of e[m,n] (symmetric e) per col n.
// ---------------------------------------------------------------------------
__global__ __launch_bounds__(256) void k_rowstats2(const f16* __restrict__ qT,
                                                   float* __restrict__ rmax,
                                                   float* __restrict__ rsum)
{
  const int b = blockIdx.y, n0 = blockIdx.x*64;
  const int tid = threadIdx.x, lane = tid & 63, w = tid >> 6;
  const int lr = lane & 15, lg = lane >> 4;
  const f16* qb = qT + (long)b*NPT*32;
  const f16x8 bfr = *(const f16x8*)(qb + (long)(n0 + w*16 + lr)*32 + lg*8);
  float mx = -1e30f, sm = 0.f;
  for (int m0=0; m0<NPT; m0+=32){
    f16x8 af0 = *(const f16x8*)(qb + (long)(m0+lr)*32 + lg*8);
    f16x8 af1 = *(const f16x8*)(qb + (long)(m0+16+lr)*32 + lg*8);
    f32x4 e0 = mfma16(af0, bfr, (f32x4){0,0,0,0});
    f32x4 e1 = mfma16(af1, bfr, (f32x4){0,0,0,0});
    float t0 = fmaxf(fmaxf(e0[0],e0[1]), fmaxf(e0[2],e0[3]));
    float t1 = fmaxf(fmaxf(e1[0],e1[1]), fmaxf(e1[2],e1[3]));
    float nm = fmaxf(mx, fmaxf(t0, t1));
    sm *= __expf(mx - nm);
    mx = nm;
    sm += __expf(e0[0]-mx) + __expf(e0[1]-mx) + __expf(e0[2]-mx) + __expf(e0[3]-mx)
        + __expf(e1[0]-mx) + __expf(e1[1]-mx) + __expf(e1[2]-mx) + __expf(e1[3]-mx);
  }
  #pragma unroll
  for (int d=16; d<64; d<<=1){
    float omx = __shfl_xor(mx, d, 64);
    float osm = __shfl_xor(sm, d, 64);
    float nm = fmaxf(mx, omx);
    sm = sm*__expf(mx-nm) + osm*__expf(omx-nm);
    mx = nm;
  }
  if (lane < 16){
    rmax[(long)b*NPT + n0 + w*16 + lr] = mx;
    rsum[(long)b*NPT + n0 + w*16 + lr] = sm;
  }
}

// ---------------------------------------------------------------------------
// pass2 PARTIAL with 2-deep pipelined V staging (one barrier per tile):
// per segment seg, n in [seg*512, seg*512+512):
//   xrpart[(b*NSEG+seg)][m][c] = sum_n p[n,m] v[c,n]   (f16 raw)
//   cspart[(b*NSEG+seg)*NPT + m] = sum_n p[n,m]        (fp32, ones-MFMA)
// Race audit: iter stages vs[cur^1], reads vs[cur]; end-of-iter barrier
// orders both hazards. ps rows wave-private (no barrier). grid (32,NSEG,B).
// ---------------------------------------------------------------------------
__global__ __launch_bounds__(256) void k_pass2p(const f16* __restrict__ qT,
                                                const f16* __restrict__ v16,
                                                const float* __restrict__ rmax,
                                                const float* __restrict__ rsum,
                                                f16* __restrict__ xrpart,
                                                float* __restrict__ cspart)
{
  __shared__ __align__(16) f16 ps[64][40];      // pT[m][n-tile]; rows wave-private
  __shared__ __align__(16) f16 vs[2][128][40];  // double-buffered v-tile [c][n-tile]
  const int b = blockIdx.z, seg = blockIdx.y, m0 = blockIdx.x*64;
  const int tid = threadIdx.x, lane = tid & 63, w = tid >> 6;
  const int lr = lane & 15, lg = lane >> 4;
  const f16* qb = qT + (long)b*NPT*32;
  const f16* vb = v16 + (long)b*128*NPT;
  const float* rmx = rmax + (long)b*NPT;
  const float* rsm = rsum + (long)b*NPT;
  const f16x8 afe = *(const f16x8*)(qb + (long)(m0 + w*16 + lr)*32 + lg*8);  // E A-frag (rows m)
  f16x8 ones;
  #pragma unroll
  for (int j=0;j<8;++j) ones[j] = (f16)1.0f;
  f32x4 acc[8];
  #pragma unroll
  for (int cg=0; cg<8; ++cg) acc[cg] = (f32x4){0,0,0,0};
  f32x4 acc_cs = (f32x4){0,0,0,0};

  const int ntBeg = seg*(NPT/NSEG), ntEnd = ntBeg + NPT/NSEG;
  // prologue: stage first tile into vs[0]
  #pragma unroll
  for (int g = tid; g < 512; g += 256){
    int c = g>>2, s = g&3;
    *(float4*)&vs[0][c][s*8] = *(const float4*)(vb + (long)c*NPT + ntBeg + s*8);
  }
  __syncthreads();
  int cur = 0;

  for (int nt=ntBeg; nt<ntEnd; nt+=32){
    // issue next tile's staging into vs[cur^1] (loads fly under E+PV compute)
    if (nt + 32 < ntEnd){
      #pragma unroll
      for (int g = tid; g < 512; g += 256){
        int c = g>>2, s = g&3;
        *(float4*)&vs[cur^1][c][s*8] = *(const float4*)(vb + (long)c*NPT + nt + 32 + s*8);
      }
    }
    // E phase: 2 col-groups; lane col n fixed, 4 m-rows (ps wave-private)
    #pragma unroll
    for (int ng=0; ng<2; ++ng){
      f16x8 bfe = *(const f16x8*)(qb + (long)(nt + ng*16 + lr)*32 + lg*8);
      f32x4 e = mfma16(afe, bfe, (f32x4){0,0,0,0});
      const int n = nt + ng*16 + lr;
      const float rm = rmx[n];
      const float irs = 1.f / rsm[n];
      #pragma unroll
      for (int i=0;i<4;++i){
        float p = __expf(e[i] - rm) * irs;
        ps[w*16 + lg*4 + i][ng*16 + lr] = (f16)p;
      }
    }
    // PV phase: A = pT rows m (wave-private), B = current v-tile
    f16x8 ap = *(const f16x8*)&ps[w*16 + lr][lg*8];
    #pragma unroll
    for (int cg=0; cg<8; ++cg){
      f16x8 bp = *(const f16x8*)&vs[cur][cg*16 + lr][lg*8];
      acc[cg] = mfma16(ap, bp, acc[cg]);
    }
    acc_cs = mfma16(ap, ones, acc_cs);   // colsum on matrix pipe
    __syncthreads();                      // drains staging; protects vs[cur] reuse
    cur ^= 1;
  }
  const long row = (long)(b*NSEG + seg);
  // acc_cs[i] = cs[m0 + w*16 + lg*4 + i], duplicated across lr
  if (lr == 0){
    #pragma unroll
    for (int i=0;i<4;++i)
      cspart[row*NPT + m0 + w*16 + lg*4 + i] = acc_cs[i];
  }
  // raw partial store (no renorm)
  f16* xb = xrpart + row*NPT*128;
  #pragma unroll
  for (int cg=0; cg<8; ++cg)
    #pragma unroll
    for (int i=0;i<4;++i)
      xb[(long)(m0 + w*16 + lg*4 + i)*128 + cg*16 + lr] = (f16)acc[cg][i];
}

// ---------------------------------------------------------------------------
// merge NSEG partials: xrT[b][m][c] = (sum_s xrpart)/(1e-9 + sum_s cspart)
// ---------------------------------------------------------------------------
__global__ __launch_bounds__(256) void k_pmerge(const f16* __restrict__ xrpart,
                                                const float* __restrict__ cspart,
                                                f16* __restrict__ xrT)
{
  const long idx = (long)blockIdx.x*256 + threadIdx.x;   // 0..524287
  const long gm = idx >> 4;          // b*2048 + m
  const int  c0 = (int)(idx & 15) * 8;
  const long b = gm >> 11, m = gm & 2047;
  const long r0 = (b*NSEG) * (long)NPT + m;              // row base in [B*NSEG][NPT]
  float cs = 0.f;
  #pragma unroll
  for (int s=0;s<NSEG;++s) cs += cspart[r0 + (long)s*NPT];
  const float inv = 1.f/(1e-9f + cs);
  float a8[8];
  #pragma unroll
  for (int j=0;j<8;++j) a8[j] = 0.f;
  #pragma unroll
  for (int s=0;s<NSEG;++s){
    f16x8 v = *(const f16x8*)(xrpart + (r0 + (long)s*NPT)*128 + c0);
    #pragma unroll
    for (int j=0;j<8;++j) a8[j] += (float)v[j];
  }
  f16x8 ov;
  #pragma unroll
  for (int j=0;j<8;++j) ov[j] = (f16)(a8[j]*inv);
  *(f16x8*)(xrT + gm*128 + c0) = ov;
}

// ---------------------------------------------------------------------------
// xT = prev + lfT (fp16 vector add)
// ---------------------------------------------------------------------------
__global__ __launch_bounds__(256) void k_addT(const f16* __restrict__ prev, int prs, int pcol,
                                              const f16* __restrict__ lfT,
                                              f16* __restrict__ xT)
{
  long idx = (long)blockIdx.x*256 + threadIdx.x;
  long bn = idx >> 4; int c8 = (int)(idx & 15);
  f16x8 a = *(const f16x8*)(prev + bn*prs + pcol + c8*8);
  f16x8 l = *(const f16x8*)(lfT + bn*128 + c8*8);
  *(f16x8*)(xT + bn*128 + c8*8) = a + l;
}

// ---------------------------------------------------------------------------
// gmax over n per (b,c)
// ---------------------------------------------------------------------------
__global__ __launch_bounds__(1024) void k_gmaxT(const f16* __restrict__ lfT,
                                                float* __restrict__ gmaxv)
{
  __shared__ float red[8][128];
  const int b = blockIdx.x;
  const int c = threadIdx.x & 127, h = threadIdx.x >> 7;
  const f16* p = lfT + (long)b*NPT*128;
  float m = -1e30f;
  for (int n = h*256; n < (h+1)*256; ++n) m = fmaxf(m, (float)p[(long)n*128 + c]);
  red[h][c] = m; __syncthreads();
  if (threadIdx.x < 128){
    float mm = red[0][c];
    #pragma unroll
    for (int j=1;j<8;++j) mm = fmaxf(mm, red[j][c]);
    gmaxv[b*128 + c] = mm;
  }
}

__global__ __launch_bounds__(128) void k_gvec(const float* __restrict__ w0,
                                              const float* __restrict__ b0,
                                              const float* __restrict__ gmaxv,
                                              float* __restrict__ gc)
{
  const int b = blockIdx.x, o = threadIdx.x;
  __shared__ float g[128];
  g[o] = gmaxv[b*128+o]; __syncthreads();
  float acc = b0[o];
  for (int c = 0; c < 128; ++c) acc = fmaf(w0[o*256 + 128 + c], g[c], acc);
  gc[b*128+o] = acc;
}

// ---------------------------------------------------------------------------
// SA epilogue GEMM
// ---------------------------------------------------------------------------
__global__ __launch_bounds__(256) void k_safin(
    const f16* __restrict__ Wt, const float* __restrict__ bt,
    const float* __restrict__ g, const float* __restrict__ be,
    const f16* __restrict__ xT, const f16* __restrict__ xrT,
    f16* __restrict__ cat, int Lcol)
{
  __shared__ __align__(16) f16 Xs[64][72];
  __shared__ __align__(16) f16 Wsh[64][72];
  const int b  = blockIdx.z;
  const int n0 = blockIdx.x * 64;
  const int o0 = blockIdx.y * 64;
  const int tid = threadIdx.x, lane = tid & 63, w = tid >> 6;
  const int lr = lane & 15, lg = lane >> 4;
  const int wn = w>>1, wo = w&1;
  const f16* xb  = xT  + (long)b*NPT*128;
  const f16* xrb = xrT + (long)b*NPT*128;
  f32x4 acc[2][2];
  #pragma unroll
  for (int ni=0;ni<2;++ni){ acc[ni][0]=(f32x4){0,0,0,0}; acc[ni][1]=(f32x4){0,0,0,0}; }

  for (int k0=0; k0<128; k0+=64){
    #pragma unroll
    for (int gidx = tid; gidx < 512; gidx += 256){
      int r = gidx>>3, s = gidx&7;
      f16x8 xa = *(const f16x8*)(xb  + (long)(n0+r)*128 + k0 + s*8);
      f16x8 xr = *(const f16x8*)(xrb + (long)(n0+r)*128 + k0 + s*8);
      *(f16x8*)&Xs[r][s*8] = xa - xr;
      *(float4*)&Wsh[r][s*8] = *(const float4*)(Wt + (long)(o0+r)*128 + k0 + s*8);
    }
    __syncthreads();
    #pragma unroll
    for (int ks=0; ks<2; ++ks){
      f16x8 a[2], bf[2];
      #pragma unroll
      for (int ni=0;ni<2;++ni) a[ni] = *(const f16x8*)&Xs[wn*32 + ni*16 + lr][ks*32 + lg*8];
      #pragma unroll
      for (int oi=0;oi<2;++oi) bf[oi] = *(const f16x8*)&Wsh[wo*32 + oi*16 + lr][ks*32 + lg*8];
      #pragma unroll
      for (int ni=0;ni<2;++ni)
        #pragma unroll
        for (int oi=0;oi<2;++oi) acc[ni][oi] = mfma16(a[ni], bf[oi], acc[ni][oi]);
    }
    __syncthreads();
  }
  const float bnsc = rsqrtf(1.f + 1e-5f);
  #pragma unroll
  for (int ni=0;ni<2;++ni)
    #pragma unroll
    for (int oi=0;oi<2;++oi){
      const int oc = o0 + wo*32 + oi*16 + lr;
      const float bti = bt[oc], gi = g[oc]*bnsc, bei = be[oc];
      #pragma unroll
      for (int i=0;i<4;++i){
        const int nn = n0 + wn*32 + ni*16 + lg*4 + i;
        float t = acc[ni][oi][i] + bti;
        float val = fmaxf(fmaf(gi, t, bei), 0.f);
        float res = (float)xb[(long)nn*128 + oc];
        cat[(long)b*NPT*384 + (long)nn*384 + Lcol + oc] = (f16)(res + val);
      }
    }
}

__global__ __launch_bounds__(256) void k_maxfinal(const float* __restrict__ part,
                                                  float* __restrict__ out)
{
  const int t = blockIdx.x*256 + threadIdx.x;   // 0..16383
  float m = -1e30f;
  #pragma unroll
  for (int j=0;j<16;++j) m = fmaxf(m, part[(long)t*16 + j]);
  out[t] = m;
}

// ---------------------------------------------------------------------------
extern "C" void kernel_launch(void* const* d_in, const int* in_sizes, int n_in,
                              void* d_out, int out_size, void* d_ws, size_t ws_size,
                              hipStream_t stream)
{
  const float* in   = (const float*)d_in[0];
  const float* m1w0 = (const float*)d_in[1];
  const float* m1b0 = (const float*)d_in[2];
  const float* m1w1 = (const float*)d_in[3];
  const float* m1b1 = (const float*)d_in[4];
  const float* m2w0 = (const float*)d_in[5];
  const float* m2b0 = (const float*)d_in[6];
  const float* m2w1 = (const float*)d_in[7];
  const float* m2b1 = (const float*)d_in[8];
  const float* m3w0 = (const float*)d_in[9];
  const float* m3b0 = (const float*)d_in[10];
  const float* m3w1 = (const float*)d_in[11];
  const float* m3b1 = (const float*)d_in[12];

  // ws layout (halfs)
  f16* ws16 = (f16*)d_ws;
  f16* W16  = ws16;                       // 880,640
  f16* lfT  = ws16 + 880640;              // [B][N][128]
  f16* xT   = ws16 + 5074944;             // [B][N][128]
  f16* qT   = ws16 + 9269248;             // [B][N][32]
  f16* vbuf = ws16 + 10317824;            // [B][128][N]
  f16* xrT  = ws16 + 14512128;            // [B][N][128] (also mlp2 features)
  f16* hT   = ws16 + 18706432;            // [B][N][512] (mlp hidden)
  f16* xrpart = hT;                       // [B*NSEG][N][128] — aliases hT (dead during SA)
  f16* catT = ws16 + 35483648;            // [B][N][384]
  float* fb = (float*)(ws16 + 48066560);
  float* rmaxp  = fb;                     // [B,N]
  float* rsump  = fb + 32768;             // [B,N]
  float* gmaxv  = fb + 65536;             // [B,128]
  float* gc     = fb + 67584;             // [B,128]
  float* part   = fb + 69632;             // [B,1024,16]
  float* cspart = fb + 593920;            // [B*NSEG][N]

  const dim3 blk(256);

  k_wconv<<<dim3((WTOT+255)/256), blk, 0, stream>>>(
      m1w1, m2w0, m2w1, m3w0, m3w1,
      (const float*)d_in[13], (const float*)d_in[14], (const float*)d_in[16],
      (const float*)d_in[20], (const float*)d_in[21], (const float*)d_in[23],
      (const float*)d_in[27], (const float*)d_in[28], (const float*)d_in[30],
      W16);

  // mlp1
  k_mlp1aT<<<dim3(NBAT*NPT*32/256), blk, 0, stream>>>(in, m1w0, m1b0, hT);
  gemmT<64,false,false><<<dim3(32,2,NBAT), blk, 0, stream>>>(
      W16+OFF_M1W1, m1b1, nullptr, hT, 128, lfT, 128, 0, 128);
  // global max + mlp2
  k_gmaxT<<<dim3(NBAT), dim3(1024), 0, stream>>>(lfT, gmaxv);
  k_gvec<<<dim3(NBAT), dim3(128), 0, stream>>>(m2w0, m2b0, gmaxv, gc);
  gemmT<64,true,true><<<dim3(32,2,NBAT), blk, 0, stream>>>(
      W16+OFF_M2W0A, nullptr, gc, lfT, 128, hT, 128, 0, 128);
  gemmT<64,false,false><<<dim3(32,2,NBAT), blk, 0, stream>>>(
      W16+OFF_M2W1, m2b1, nullptr, hT, 128, xrT, 128, 0, 128);   // features -> xrT

  // 3 SA layers
  for (int L = 0; L < 3; ++L){
    const float* bv = (const float*)d_in[13 + L*7 + 2];
    const float* bt = (const float*)d_in[13 + L*7 + 4];
    const float* gg = (const float*)d_in[13 + L*7 + 5];
    const float* be = (const float*)d_in[13 + L*7 + 6];
    const f16* wq16 = W16 + OFF_SA + L*SA_STRIDE;
    const f16* wv16 = wq16 + 4096;
    const f16* wt16 = wq16 + 20480;

    const f16* prev = (L==0) ? xrT : (catT + (long)(L-1)*128);
    const int  prs  = (L==0) ? 128 : 384;
    k_addT<<<dim3(NBAT*NPT*16/256), blk, 0, stream>>>(prev, prs, 0, lfT, xT);

    gemmT<32,false,false><<<dim3(32,1,NBAT), blk, 0, stream>>>(
        wq16, nullptr, nullptr, xT, 128, qT, 32, 0, 128);
    vgemm<<<dim3(32,2,NBAT), blk, 0, stream>>>(wv16, bv, xT, vbuf);
    k_rowstats2<<<dim3(32,NBAT), blk, 0, stream>>>(qT, rmaxp, rsump);
    k_pass2p<<<dim3(32,NSEG,NBAT), blk, 0, stream>>>(qT, vbuf, rmaxp, rsump, xrpart, cspart);
    k_pmerge<<<dim3(2048), blk, 0, stream>>>(xrpart, cspart, xrT);
    k_safin<<<dim3(32,2,NBAT), blk, 0, stream>>>(wt16, bt, gg, be, xT, xrT, catT, L*128);
  }

  // mlp3: layer0 (384->512 relu) 128x128 tile, layer1 fused-max 128x128
  gemm128<true><<<dim3(16,4,NBAT), blk, 0, stream>>>(
      W16+OFF_M3W0, m3b0, catT, 384, hT, 512, 384);
  k_gemmax128<<<dim3(16,8,NBAT), blk, 0, stream>>>(W16+OFF_M3W1, m3b1, hT, part);
  k_maxfinal<<<dim3(64), blk, 0, stream>>>(part, (float*)d_out);
}